// Round 8
// baseline (1375.179 us; speedup 1.0000x reference)
//
#include <hip/hip_runtime.h>

#define H_ 8
#define B_ 8
#define S_ 2048
#define D_ 256

// padded LDS strides (halves): kill 8/16-way bank conflicts, keep 16B alignment
#define KSTRIDE 264   // k-tile rows: 528B = 4 banks offset/row
#define VSTRIDE 40    // 32-col tiles: 80B = 20 banks offset/row
#define QTSTRIDE 136  // q-transpose rows: 128 d + pad, 272B = 16B-aligned

typedef __attribute__((ext_vector_type(8))) _Float16 half8;
typedef __attribute__((ext_vector_type(4))) _Float16 half4v;
typedef __attribute__((ext_vector_type(2))) _Float16 half2v;
typedef __attribute__((ext_vector_type(4))) float f32x4;

// split 8 consecutive fp32 into fp16 hi + lo residual
__device__ inline void split8(const float* __restrict__ p, half8& hv, half8& lv) {
  float4 a = *(const float4*)p, b = *(const float4*)(p + 4);
  hv[0] = (_Float16)a.x; hv[1] = (_Float16)a.y; hv[2] = (_Float16)a.z; hv[3] = (_Float16)a.w;
  hv[4] = (_Float16)b.x; hv[5] = (_Float16)b.y; hv[6] = (_Float16)b.z; hv[7] = (_Float16)b.w;
  lv[0] = (_Float16)(a.x - (float)hv[0]); lv[1] = (_Float16)(a.y - (float)hv[1]);
  lv[2] = (_Float16)(a.z - (float)hv[2]); lv[3] = (_Float16)(a.w - (float)hv[3]);
  lv[4] = (_Float16)(b.x - (float)hv[4]); lv[5] = (_Float16)(b.y - (float)hv[5]);
  lv[6] = (_Float16)(b.z - (float)hv[6]); lv[7] = (_Float16)(b.w - (float)hv[7]);
}

// ------- transpose + split weights via LDS tile: W[h][f][d] -> Wt hi/lo [h][d][f] -------
__global__ void split_w_kernel(const float* __restrict__ W,
                               _Float16* __restrict__ thi, _Float16* __restrict__ tlo) {
  __shared__ float t[64][65];
  const int h = blockIdx.z, f0 = blockIdx.x * 64, d0 = blockIdx.y * 64;
  const int col = threadIdx.x & 63, rg = threadIdx.x >> 6;
#pragma unroll
  for (int it = 0; it < 16; ++it) {
    int f = rg * 16 + it;
    t[f][col] = W[((size_t)h * 256 + f0 + f) * 256 + d0 + col];
  }
  __syncthreads();
#pragma unroll
  for (int it = 0; it < 16; ++it) {
    int d = rg * 16 + it;
    float v = t[col][d];
    _Float16 hv = (_Float16)v;
    size_t idx = ((size_t)h * 256 + d0 + d) * 256 + f0 + col;
    thi[idx] = hv;
    tlo[idx] = (_Float16)(v - (float)hv);
  }
}

// ---------------- out = Cb broadcast ----------------
__global__ void out_init_kernel(float* __restrict__ out, const float* __restrict__ Cb) {
  int i = blockIdx.x * blockDim.x + threadIdx.x;
  if (i < B_ * S_ * 8) out[i] = Cb[i & 7];
}

// ---- projection GEMM (R10's best-measured config — FROZEN) ----
// Used for K (VMODE 2) and V (VMODE 1) only; q-proj is fused into flash (R19).
template <int VMODE>
__global__ __launch_bounds__(256, 2) void proj_kernel(
    const float* __restrict__ A,
    const _Float16* __restrict__ Whi, const _Float16* __restrict__ Wlo,
    const float* __restrict__ bias, float oscale, int h0,
    _Float16* __restrict__ Ohi, _Float16* __restrict__ Olo) {
  constexpr bool TMULT = (VMODE != 1);
  __shared__ _Float16 a_hi[128 * VSTRIDE] __attribute__((aligned(16)));
  __shared__ _Float16 b_hi[128 * VSTRIDE] __attribute__((aligned(16)));
  __shared__ _Float16 a_lo[TMULT ? 128 * VSTRIDE : 8] __attribute__((aligned(16)));
  __shared__ _Float16 b_lo[TMULT ? 128 * VSTRIDE : 8] __attribute__((aligned(16)));
  const int tid = threadIdx.x;
  const int w = tid >> 6, lane = tid & 63;
  const int quad = lane >> 4, l15 = lane & 15;
  const int hb = blockIdx.z, h = h0 + (hb >> 3), b = hb & 7;
  const int s0 = blockIdx.x * 128, d0 = blockIdx.y * 128;
  const int wr = w >> 1, wc = w & 1;
  const f32x4 fz = {0.f, 0.f, 0.f, 0.f};
  f32x4 acc[4][4];
#pragma unroll
  for (int i = 0; i < 4; ++i)
#pragma unroll
    for (int j = 0; j < 4; ++j) acc[i][j] = fz;
  const size_t arow0 = (size_t)b * S_ + s0;
  const size_t wrow0 = (size_t)h * 256 + d0;
  for (int kk = 0; kk < 8; ++kk) {
    const int f0 = kk * 32;
    __syncthreads();
#pragma unroll
    for (int i = 0; i < 2; ++i) {
      int cc = i * 256 + tid;
      int r = cc >> 2, ch = (cc & 3) * 8;
      half8 hv, lv;
      split8(A + (arow0 + r) * 256 + f0 + ch, hv, lv);
      *(half8*)&a_hi[r * VSTRIDE + ch] = hv;
      size_t woff = (wrow0 + r) * 256 + f0 + ch;
      *(half8*)&b_hi[r * VSTRIDE + ch] = *(const half8*)(Whi + woff);
      if (TMULT) {
        *(half8*)&a_lo[r * VSTRIDE + ch] = lv;
        *(half8*)&b_lo[r * VSTRIDE + ch] = *(const half8*)(Wlo + woff);
      }
    }
    __syncthreads();
    half8 afh[4], afl[4], bfh[4], bfl[4];
#pragma unroll
    for (int t = 0; t < 4; ++t) {
      int ar = wr * 64 + t * 16 + l15;
      afh[t] = *(const half8*)&a_hi[ar * VSTRIDE + quad * 8];
      int br = wc * 64 + t * 16 + l15;
      bfh[t] = *(const half8*)&b_hi[br * VSTRIDE + quad * 8];
      if (TMULT) {
        afl[t] = *(const half8*)&a_lo[ar * VSTRIDE + quad * 8];
        bfl[t] = *(const half8*)&b_lo[br * VSTRIDE + quad * 8];
      }
    }
#pragma unroll
    for (int rf = 0; rf < 4; ++rf)
#pragma unroll
      for (int cf = 0; cf < 4; ++cf) {
        acc[rf][cf] = __builtin_amdgcn_mfma_f32_16x16x32_f16(afh[rf], bfh[cf], acc[rf][cf], 0, 0, 0);
        if (TMULT) {
          acc[rf][cf] = __builtin_amdgcn_mfma_f32_16x16x32_f16(afh[rf], bfl[cf], acc[rf][cf], 0, 0, 0);
          acc[rf][cf] = __builtin_amdgcn_mfma_f32_16x16x32_f16(afl[rf], bfh[cf], acc[rf][cf], 0, 0, 0);
        }
      }
  }
  // epilogue: C/D layout row = quad*4+reg (s), col = lane&15 (d)
#pragma unroll
  for (int rf = 0; rf < 4; ++rf) {
#pragma unroll
    for (int cf = 0; cf < 4; ++cf) {
      const int d = d0 + wc * 64 + cf * 16 + l15;
      const float bv = bias[h * 256 + d];
      if (VMODE != 1) {
#pragma unroll
        for (int r = 0; r < 4; ++r) {
          const int s = s0 + wr * 64 + rf * 16 + quad * 4 + r;
          float val = (acc[rf][cf][r] + bv) * oscale;
          _Float16 hvv = (_Float16)val;
          size_t idx = ((size_t)hb * S_ + s) * 256 + d;
          Ohi[idx] = hvv;
          if (VMODE == 0) Olo[idx] = (_Float16)(val - (float)hvv);
        }
      } else {
        // lane holds 4 consecutive s for fixed d -> coalesced half4 store along S
        half4v pack;
#pragma unroll
        for (int r = 0; r < 4; ++r) pack[r] = (_Float16)((acc[rf][cf][r] + bv) * oscale);
        size_t idx = ((size_t)hb * 256 + d) * S_ + s0 + wr * 64 + rf * 16 + quad * 4;
        *(half4v*)(Ohi + idx) = pack;
      }
    }
  }
}

// ---------------- flash attention + fused Q-projection + fused C-projection ----------------
// R19: q-proj fused as prologue. R20: head-pinning (null result: FETCH 590->560 only —
// L2 working set 16MB K/V streaming >> 4MB, Qw can't survive; cache tricks dead end).
// R21 (this round): 512-thread / 8-wave blocks, 128 q-rows each -> block count halves
// (2048->1024) -> Qw re-read traffic halves (512->256MB). Per-wave structure (16 q-rows,
// same MFMA sequences) identical to R19/R1 — does NOT re-enter the R16-R18 register wall.
// LDS: single 61.4KB arena aliased across {prologue Qw/bo | kt K/V/P | q-transpose},
// phases separated by the existing barriers. Transpose phases reordered dh-major so
// qacc frees before qfh/qfl fill (reg peak ~96 < 128 cap from launch_bounds(512,4)).
__global__ __launch_bounds__(512, 4) void flash_kernel(
    const float* __restrict__ bo,
    const _Float16* __restrict__ qwhi, const _Float16* __restrict__ qwlo,
    const float* __restrict__ qbias,
    const _Float16* __restrict__ khi,
    const _Float16* __restrict__ vt, const float* __restrict__ Cw,
    float* __restrict__ out, int h0) {
  // one aliased LDS arena, 30720 halves = 61440B (static limit 64KB, 2 blocks/CU = 123KB/160KB)
  __shared__ _Float16 smem[30720] __attribute__((aligned(16)));
  _Float16* khi_s = smem;                    // kt: 32*KSTRIDE  = 8448
  _Float16* vt_s  = smem + 8448;             // kt: 256*VSTRIDE = 10240
  _Float16* p_s   = smem + 18688;            // kt: 8 waves * 16*VSTRIDE = 5120
  _Float16* qw_hi = smem;                    // prologue: 256*VSTRIDE = 10240
  _Float16* qw_lo = smem + 10240;            // prologue: 10240
  _Float16* bo_hi = smem + 20480;            // prologue: 128*VSTRIDE = 5120
  _Float16* bo_lo = smem + 25600;            // prologue: 5120
  _Float16* qtb   = smem;                    // transpose: 128*QTSTRIDE = 17408
  const int tid = threadIdx.x, w = tid >> 6, lane = tid & 63;
  const int quad = lane >> 4, l15 = lane & 15;
  // head-pinning remap kept from R20 (harmless): hloc = bid % nheads
  const int nheads = gridDim.y >> 3;  // HC
  const int bid = blockIdx.x + gridDim.x * blockIdx.y;
  const int hloc = bid % nheads;
  const int rr = bid / nheads;
  const int b = rr & 7;
  const int qblk = rr >> 3;            // 0..15
  const int h = h0 + hloc;
  const int hb = hloc * 8 + b;
  const int qbase = qblk * 128;        // block owns 128 q-rows; wave w owns rows w*16..+15

  // ---- fused q projection: qacc[df] = (bo rows w*16+l15) x (Qw^T), all 256 d ----
  const f32x4 fz = {0.f, 0.f, 0.f, 0.f};
  f32x4 qacc[16];
#pragma unroll
  for (int df = 0; df < 16; ++df) qacc[df] = fz;
  for (int kk = 0; kk < 8; ++kk) {
    __syncthreads();
    // stage Qw^T hi/lo: [256 d][32 f], 2 half8/thread each
#pragma unroll
    for (int i = 0; i < 2; ++i) {
      int c = i * 512 + tid;
      int dr = c >> 2, ch = (c & 3) * 8;
      size_t woff = ((size_t)h * 256 + dr) * 256 + kk * 32 + ch;
      *(half8*)&qw_hi[dr * VSTRIDE + ch] = *(const half8*)(qwhi + woff);
      *(half8*)&qw_lo[dr * VSTRIDE + ch] = *(const half8*)(qwlo + woff);
    }
    // stage bo hi/lo: [128 s][32 f], 1 split8/thread
    {
      int rrow = tid >> 2, ch = (tid & 3) * 8;
      half8 hv, lv;
      split8(bo + ((size_t)b * S_ + qbase + rrow) * 256 + kk * 32 + ch, hv, lv);
      *(half8*)&bo_hi[rrow * VSTRIDE + ch] = hv;
      *(half8*)&bo_lo[rrow * VSTRIDE + ch] = lv;
    }
    __syncthreads();
    half8 bh = *(const half8*)&bo_hi[(w * 16 + l15) * VSTRIDE + quad * 8];
    half8 bl = *(const half8*)&bo_lo[(w * 16 + l15) * VSTRIDE + quad * 8];
#pragma unroll
    for (int df = 0; df < 16; ++df) {
      half8 awh = *(const half8*)&qw_hi[(df * 16 + l15) * VSTRIDE + quad * 8];
      half8 awl = *(const half8*)&qw_lo[(df * 16 + l15) * VSTRIDE + quad * 8];
      // order matches proj<0>: a_hi*w_hi, a_hi*w_lo, a_lo*w_hi
      qacc[df] = __builtin_amdgcn_mfma_f32_16x16x32_f16(awh, bh, qacc[df], 0, 0, 0);
      qacc[df] = __builtin_amdgcn_mfma_f32_16x16x32_f16(awl, bh, qacc[df], 0, 0, 0);
      qacc[df] = __builtin_amdgcn_mfma_f32_16x16x32_f16(awh, bl, qacc[df], 0, 0, 0);
    }
  }
  // ---- bias + scale + hi/lo split + 4-phase LDS transpose into qfh/qfl ----
  // dh-major phase order (hi,lo per d-half) so qacc[0..7] dies before qfh/qfl[4..7] fill.
  half8 qfh[8], qfl[8];
#pragma unroll
  for (int ph = 0; ph < 4; ++ph) {
    const int dh = ph >> 1;        // which 128-d half
    const bool lo = ph & 1;
    __syncthreads();
#pragma unroll
    for (int dfi = 0; dfi < 8; ++dfi) {
      int df = dh * 8 + dfi;
#pragma unroll
      for (int rp = 0; rp < 2; ++rp) {
        half2v hw;
#pragma unroll
        for (int rr2 = 0; rr2 < 2; ++rr2) {
          int r = rp * 2 + rr2;
          float bv = qbias[h * 256 + df * 16 + quad * 4 + r];
          float val = (qacc[df][r] + bv) * 0.0625f;  // softmax 1/16 folded in
          _Float16 hv = (_Float16)val;
          hw[rr2] = lo ? (_Float16)(val - (float)hv) : hv;
        }
        *(half2v*)&qtb[(w * 16 + l15) * QTSTRIDE + dfi * 16 + quad * 4 + rp * 2] = hw;
      }
    }
    __syncthreads();
#pragma unroll
    for (int k2 = 0; k2 < 4; ++k2) {
      half8 v = *(const half8*)&qtb[(w * 16 + l15) * QTSTRIDE + k2 * 32 + quad * 8];
      if (lo) qfl[dh * 4 + k2] = v;
      else    qfh[dh * 4 + k2] = v;
    }
  }

  // ---- kt-loop: per-wave byte-identical to R1 ----
  f32x4 o_acc[16];
#pragma unroll
  for (int df = 0; df < 16; ++df) o_acc[df] = fz;
  float m_r = -3.0e38f, l_r = 0.f;
  _Float16* psw = p_s + w * (16 * VSTRIDE);

  for (int kt = 0; kt < 64; ++kt) {
    __syncthreads();  // prior iteration's PV reads of k/v LDS are done
    {
      size_t kbase = ((size_t)hb * S_ + kt * 32) * 256;
#pragma unroll
      for (int i = 0; i < 2; ++i) {
        int cc = i * 512 + tid;
        int kr = cc >> 5, kch = (cc & 31) * 8;
        *(half8*)&khi_s[kr * KSTRIDE + kch] = *(const half8*)(khi + kbase + kr * 256 + kch);
        int vd = cc >> 2, vch = (cc & 3) * 8;
        size_t voff = ((size_t)hb * 256 + vd) * S_ + kt * 32 + vch;
        *(half8*)&vt_s[vd * VSTRIDE + vch] = *(const half8*)(vt + voff);
      }
    }
    __syncthreads();
    // QK^T swapped: A = K-frag, B = Q-frag. C: row = quad*4+r = k-col, col = l15 = q.
    f32x4 sc0 = fz, sc1 = fz;
#pragma unroll
    for (int ks = 0; ks < 8; ++ks) {
      half8 bh0 = *(const half8*)&khi_s[(0 * 16 + l15) * KSTRIDE + ks * 32 + quad * 8];
      sc0 = __builtin_amdgcn_mfma_f32_16x16x32_f16(bh0, qfh[ks], sc0, 0, 0, 0);
      sc0 = __builtin_amdgcn_mfma_f32_16x16x32_f16(bh0, qfl[ks], sc0, 0, 0, 0);
      half8 bh1 = *(const half8*)&khi_s[(1 * 16 + l15) * KSTRIDE + ks * 32 + quad * 8];
      sc1 = __builtin_amdgcn_mfma_f32_16x16x32_f16(bh1, qfh[ks], sc1, 0, 0, 0);
      sc1 = __builtin_amdgcn_mfma_f32_16x16x32_f16(bh1, qfl[ks], sc1, 0, 0, 0);
    }
    // online softmax, in-register: lane owns q-row l15; 2 cross-quad shfls.
    float v = fmaxf(fmaxf(fmaxf(sc0[0], sc0[1]), fmaxf(sc0[2], sc0[3])),
                    fmaxf(fmaxf(sc1[0], sc1[1]), fmaxf(sc1[2], sc1[3])));
    v = fmaxf(v, __shfl_xor(v, 16));
    v = fmaxf(v, __shfl_xor(v, 32));
    const float mn = fmaxf(m_r, v);
    const float al = __expf(m_r - mn);
    m_r = mn;
    float p0[4], p1[4], s = 0.f;
#pragma unroll
    for (int r = 0; r < 4; ++r) {
      p0[r] = __expf(sc0[r] - mn);
      p1[r] = __expf(sc1[r] - mn);
      s += p0[r] + p1[r];
    }
    s += __shfl_xor(s, 16);
    s += __shfl_xor(s, 32);
    l_r = l_r * al + s;
    // P -> LDS: psw[q=l15][k=quad*4+r (+16 for tile1)], packed half2 stores
    {
      _Float16* pb = &psw[l15 * VSTRIDE + quad * 4];
      half2v w0 = {(_Float16)p0[0], (_Float16)p0[1]};
      half2v w1 = {(_Float16)p0[2], (_Float16)p0[3]};
      half2v w2 = {(_Float16)p1[0], (_Float16)p1[1]};
      half2v w3 = {(_Float16)p1[2], (_Float16)p1[3]};
      *(half2v*)(pb) = w0;
      *(half2v*)(pb + 2) = w1;
      *(half2v*)(pb + 16) = w2;
      *(half2v*)(pb + 18) = w3;
    }
    // rescale O accumulator: gather al for o-rows quad*4+r (held at lane l15==row)
    float al_r[4];
#pragma unroll
    for (int r = 0; r < 4; ++r) al_r[r] = __shfl(al, quad * 4 + r);
#pragma unroll
    for (int df = 0; df < 16; ++df)
#pragma unroll
      for (int r = 0; r < 4; ++r) o_acc[df][r] *= al_r[r];
    __syncthreads();  // phase barrier: keeps softmax and PV LDS phases aligned
    // PV: P in A-layout from LDS, V^T as B operand
    half8 pf = *(const half8*)&psw[l15 * VSTRIDE + quad * 8];
#pragma unroll
    for (int df = 0; df < 16; ++df) {
      half8 vf = *(const half8*)&vt_s[(df * 16 + l15) * VSTRIDE + quad * 8];
      o_acc[df] = __builtin_amdgcn_mfma_f32_16x16x32_f16(pf, vf, o_acc[df], 0, 0, 0);
    }
  }
  // epilogue: normalize + fused C-projection out[b,s,j] += sum_d o*Cw
  float rcl[4];
#pragma unroll
  for (int r = 0; r < 4; ++r) rcl[r] = 1.0f / __shfl(l_r, quad * 4 + r);
  float part[32];
#pragma unroll
  for (int i = 0; i < 32; ++i) part[i] = 0.f;
#pragma unroll
  for (int df = 0; df < 16; ++df) {
    const float4* cwv = (const float4*)(Cw + ((size_t)h * 256 + df * 16 + l15) * 8);
    float4 c0 = cwv[0], c1 = cwv[1];
#pragma unroll
    for (int r = 0; r < 4; ++r) {
      float ov = o_acc[df][r] * rcl[r];
      part[r * 8 + 0] += ov * c0.x;
      part[r * 8 + 1] += ov * c0.y;
      part[r * 8 + 2] += ov * c0.z;
      part[r * 8 + 3] += ov * c0.w;
      part[r * 8 + 4] += ov * c1.x;
      part[r * 8 + 5] += ov * c1.y;
      part[r * 8 + 6] += ov * c1.z;
      part[r * 8 + 7] += ov * c1.w;
    }
  }
#pragma unroll
  for (int i = 0; i < 32; ++i) {
    float v = part[i];
    v += __shfl_xor(v, 1);
    v += __shfl_xor(v, 2);
    v += __shfl_xor(v, 4);
    v += __shfl_xor(v, 8);
    part[i] = v;
  }
  if (l15 == 0) {
#pragma unroll
    for (int r = 0; r < 4; ++r) {
      int s = qbase + w * 16 + quad * 4 + r;
#pragma unroll
      for (int j = 0; j < 8; ++j)
        atomicAdd(&out[((size_t)b * S_ + s) * 8 + j], part[r * 8 + j]);
    }
  }
}

extern "C" void kernel_launch(void* const* d_in, const int* in_sizes, int n_in,
                              void* d_out, int out_size, void* d_ws, size_t ws_size,
                              hipStream_t stream) {
  const float* x  = (const float*)d_in[0];
  const float* bo = (const float*)d_in[1];
  const float* Qw = (const float*)d_in[2];
  const float* Qb = (const float*)d_in[3];
  const float* Kw = (const float*)d_in[4];
  const float* Kb = (const float*)d_in[5];
  const float* Vw = (const float*)d_in[6];
  const float* Vb = (const float*)d_in[7];
  const float* Cw = (const float*)d_in[8];
  const float* Cb = (const float*)d_in[9];
  float* out = (float*)d_out;

  const size_t NW  = (size_t)H_ * 256 * 256;
  const size_t NHB = (size_t)B_ * S_ * 256;
  const size_t ALN = 256;
  auto pad = [](size_t b) { return (b + 255) & ~(size_t)255; };

  // pick largest head-chunk HC in {8,4,2,1} whose scratch fits ws_size
  // (q hi/lo no longer materialized — only k_hi and v_t chunks)
  int HC = 8;
  while (HC > 1) {
    size_t need = 6 * pad(NW * 2) + 2 * pad((size_t)HC * NHB * 2) + ALN;
    if (need <= ws_size) break;
    HC >>= 1;
  }

  char* base = (char*)d_ws;
  size_t off = 0;
  auto carve = [&](size_t nelem) -> _Float16* {
    _Float16* p = (_Float16*)(base + off);
    off += pad(nelem * 2);
    return p;
  };
  _Float16* qwt_hi = carve(NW); _Float16* qwt_lo = carve(NW);
  _Float16* kwt_hi = carve(NW); _Float16* kwt_lo = carve(NW);
  _Float16* vwt_hi = carve(NW); _Float16* vwt_lo = carve(NW);
  const size_t NC = (size_t)HC * NHB;
  _Float16* k_hi = carve(NC);
  _Float16* v_t  = carve(NC);

  dim3 wg(4, 4, 8);
  split_w_kernel<<<wg, 256, 0, stream>>>(Qw, qwt_hi, qwt_lo);
  split_w_kernel<<<wg, 256, 0, stream>>>(Kw, kwt_hi, kwt_lo);
  split_w_kernel<<<wg, 256, 0, stream>>>(Vw, vwt_hi, vwt_lo);
  out_init_kernel<<<(B_ * S_ * 8) / 256, 256, 0, stream>>>(out, Cb);

  for (int h0 = 0; h0 < H_; h0 += HC) {
    dim3 pg(16, 2, HC * 8);
    proj_kernel<2><<<pg, 256, 0, stream>>>(x, kwt_hi, kwt_lo, Kb, 1.0f, h0, k_hi, nullptr);
    proj_kernel<1><<<pg, 256, 0, stream>>>(x, vwt_hi, vwt_lo, Vb, 1.0f, h0, v_t, nullptr);
    dim3 fg(16, HC * 8);
    flash_kernel<<<fg, 512, 0, stream>>>(bo, qwt_hi, qwt_lo, Qb, k_hi, v_t, Cw, out, h0);
  }
}

// Round 9
// 885.182 us; speedup vs baseline: 1.5536x; 1.5536x over previous
//
#include <hip/hip_runtime.h>

#define H_ 8
#define B_ 8
#define S_ 2048
#define D_ 256

// padded LDS strides (halves): kill 8/16-way bank conflicts, keep 16B alignment
#define KSTRIDE 264   // k-tile rows: 528B = 4 banks offset/row
#define VSTRIDE 40    // 32-col tiles: 80B = 20 banks offset/row
#define QTSTRIDE 136  // q-transpose rows: 128 d + pad, 272B = 16B-aligned

typedef __attribute__((ext_vector_type(8))) _Float16 half8;
typedef __attribute__((ext_vector_type(4))) _Float16 half4v;
typedef __attribute__((ext_vector_type(2))) _Float16 half2v;
typedef __attribute__((ext_vector_type(4))) float f32x4;

// split 8 consecutive fp32 into fp16 hi + lo residual
__device__ inline void split8(const float* __restrict__ p, half8& hv, half8& lv) {
  float4 a = *(const float4*)p, b = *(const float4*)(p + 4);
  hv[0] = (_Float16)a.x; hv[1] = (_Float16)a.y; hv[2] = (_Float16)a.z; hv[3] = (_Float16)a.w;
  hv[4] = (_Float16)b.x; hv[5] = (_Float16)b.y; hv[6] = (_Float16)b.z; hv[7] = (_Float16)b.w;
  lv[0] = (_Float16)(a.x - (float)hv[0]); lv[1] = (_Float16)(a.y - (float)hv[1]);
  lv[2] = (_Float16)(a.z - (float)hv[2]); lv[3] = (_Float16)(a.w - (float)hv[3]);
  lv[4] = (_Float16)(b.x - (float)hv[4]); lv[5] = (_Float16)(b.y - (float)hv[5]);
  lv[6] = (_Float16)(b.z - (float)hv[6]); lv[7] = (_Float16)(b.w - (float)hv[7]);
}

// ------- transpose + split weights via LDS tile: W[h][f][d] -> Wt hi/lo [h][d][f] -------
__global__ void split_w_kernel(const float* __restrict__ W,
                               _Float16* __restrict__ thi, _Float16* __restrict__ tlo) {
  __shared__ float t[64][65];
  const int h = blockIdx.z, f0 = blockIdx.x * 64, d0 = blockIdx.y * 64;
  const int col = threadIdx.x & 63, rg = threadIdx.x >> 6;
#pragma unroll
  for (int it = 0; it < 16; ++it) {
    int f = rg * 16 + it;
    t[f][col] = W[((size_t)h * 256 + f0 + f) * 256 + d0 + col];
  }
  __syncthreads();
#pragma unroll
  for (int it = 0; it < 16; ++it) {
    int d = rg * 16 + it;
    float v = t[col][d];
    _Float16 hv = (_Float16)v;
    size_t idx = ((size_t)h * 256 + d0 + d) * 256 + f0 + col;
    thi[idx] = hv;
    tlo[idx] = (_Float16)(v - (float)hv);
  }
}

// ---------------- out = Cb broadcast ----------------
__global__ void out_init_kernel(float* __restrict__ out, const float* __restrict__ Cb) {
  int i = blockIdx.x * blockDim.x + threadIdx.x;
  if (i < B_ * S_ * 8) out[i] = Cb[i & 7];
}

// ---- projection GEMM (R10's best-measured config — FROZEN) ----
// Used for K (VMODE 2) and V (VMODE 1) only; q-proj is fused into flash (R19).
template <int VMODE>
__global__ __launch_bounds__(256, 2) void proj_kernel(
    const float* __restrict__ A,
    const _Float16* __restrict__ Whi, const _Float16* __restrict__ Wlo,
    const float* __restrict__ bias, float oscale, int h0,
    _Float16* __restrict__ Ohi, _Float16* __restrict__ Olo) {
  constexpr bool TMULT = (VMODE != 1);
  __shared__ _Float16 a_hi[128 * VSTRIDE] __attribute__((aligned(16)));
  __shared__ _Float16 b_hi[128 * VSTRIDE] __attribute__((aligned(16)));
  __shared__ _Float16 a_lo[TMULT ? 128 * VSTRIDE : 8] __attribute__((aligned(16)));
  __shared__ _Float16 b_lo[TMULT ? 128 * VSTRIDE : 8] __attribute__((aligned(16)));
  const int tid = threadIdx.x;
  const int w = tid >> 6, lane = tid & 63;
  const int quad = lane >> 4, l15 = lane & 15;
  const int hb = blockIdx.z, h = h0 + (hb >> 3), b = hb & 7;
  const int s0 = blockIdx.x * 128, d0 = blockIdx.y * 128;
  const int wr = w >> 1, wc = w & 1;
  const f32x4 fz = {0.f, 0.f, 0.f, 0.f};
  f32x4 acc[4][4];
#pragma unroll
  for (int i = 0; i < 4; ++i)
#pragma unroll
    for (int j = 0; j < 4; ++j) acc[i][j] = fz;
  const size_t arow0 = (size_t)b * S_ + s0;
  const size_t wrow0 = (size_t)h * 256 + d0;
  for (int kk = 0; kk < 8; ++kk) {
    const int f0 = kk * 32;
    __syncthreads();
#pragma unroll
    for (int i = 0; i < 2; ++i) {
      int cc = i * 256 + tid;
      int r = cc >> 2, ch = (cc & 3) * 8;
      half8 hv, lv;
      split8(A + (arow0 + r) * 256 + f0 + ch, hv, lv);
      *(half8*)&a_hi[r * VSTRIDE + ch] = hv;
      size_t woff = (wrow0 + r) * 256 + f0 + ch;
      *(half8*)&b_hi[r * VSTRIDE + ch] = *(const half8*)(Whi + woff);
      if (TMULT) {
        *(half8*)&a_lo[r * VSTRIDE + ch] = lv;
        *(half8*)&b_lo[r * VSTRIDE + ch] = *(const half8*)(Wlo + woff);
      }
    }
    __syncthreads();
    half8 afh[4], afl[4], bfh[4], bfl[4];
#pragma unroll
    for (int t = 0; t < 4; ++t) {
      int ar = wr * 64 + t * 16 + l15;
      afh[t] = *(const half8*)&a_hi[ar * VSTRIDE + quad * 8];
      int br = wc * 64 + t * 16 + l15;
      bfh[t] = *(const half8*)&b_hi[br * VSTRIDE + quad * 8];
      if (TMULT) {
        afl[t] = *(const half8*)&a_lo[ar * VSTRIDE + quad * 8];
        bfl[t] = *(const half8*)&b_lo[br * VSTRIDE + quad * 8];
      }
    }
#pragma unroll
    for (int rf = 0; rf < 4; ++rf)
#pragma unroll
      for (int cf = 0; cf < 4; ++cf) {
        acc[rf][cf] = __builtin_amdgcn_mfma_f32_16x16x32_f16(afh[rf], bfh[cf], acc[rf][cf], 0, 0, 0);
        if (TMULT) {
          acc[rf][cf] = __builtin_amdgcn_mfma_f32_16x16x32_f16(afh[rf], bfl[cf], acc[rf][cf], 0, 0, 0);
          acc[rf][cf] = __builtin_amdgcn_mfma_f32_16x16x32_f16(afl[rf], bfh[cf], acc[rf][cf], 0, 0, 0);
        }
      }
  }
  // epilogue: C/D layout row = quad*4+reg (s), col = lane&15 (d)
#pragma unroll
  for (int rf = 0; rf < 4; ++rf) {
#pragma unroll
    for (int cf = 0; cf < 4; ++cf) {
      const int d = d0 + wc * 64 + cf * 16 + l15;
      const float bv = bias[h * 256 + d];
      if (VMODE != 1) {
#pragma unroll
        for (int r = 0; r < 4; ++r) {
          const int s = s0 + wr * 64 + rf * 16 + quad * 4 + r;
          float val = (acc[rf][cf][r] + bv) * oscale;
          _Float16 hvv = (_Float16)val;
          size_t idx = ((size_t)hb * S_ + s) * 256 + d;
          Ohi[idx] = hvv;
          if (VMODE == 0) Olo[idx] = (_Float16)(val - (float)hvv);
        }
      } else {
        // lane holds 4 consecutive s for fixed d -> coalesced half4 store along S
        half4v pack;
#pragma unroll
        for (int r = 0; r < 4; ++r) pack[r] = (_Float16)((acc[rf][cf][r] + bv) * oscale);
        size_t idx = ((size_t)hb * 256 + d) * S_ + s0 + wr * 64 + rf * 16 + quad * 4;
        *(half4v*)(Ohi + idx) = pack;
      }
    }
  }
}

// ---------------- flash attention + fused Q-projection + fused C-projection ----------------
// R19: q-proj fused as prologue. R20: head-pinning null (-2%), dropped.
// R21/R22: 512-thread / 8-wave blocks -> block count halves (2048->1024) -> Qw re-read
// traffic halves (512->256MB). R21 FAILED on launch_bounds(512,4): compiler allocated
// 64 VGPR -> everything spilled (WRITE 149MB, FETCH 3.7GB, 1230us). R22 fix:
// __launch_bounds__(512, 2) -> 2 waves/EU -> 2 waves/SIMD -> 256 VGPR cap; demand
// ~112 VGPR + 64 AGPR = 176. Occupancy 1 block x 8 waves/CU = 2 waves/SIMD, same
// wave-level latency hiding as R6's 2x4-wave blocks (R18's 1-wave/SIMD penalty N/A).
// LDS: single 61.4KB arena aliased {prologue Qw/bo | kt K/V/P | q-transpose}.
__global__ __launch_bounds__(512, 2) void flash_kernel(
    const float* __restrict__ bo,
    const _Float16* __restrict__ qwhi, const _Float16* __restrict__ qwlo,
    const float* __restrict__ qbias,
    const _Float16* __restrict__ khi,
    const _Float16* __restrict__ vt, const float* __restrict__ Cw,
    float* __restrict__ out, int h0) {
  // one aliased LDS arena, 30720 halves = 61440B
  __shared__ _Float16 smem[30720] __attribute__((aligned(16)));
  _Float16* khi_s = smem;                    // kt: 32*KSTRIDE  = 8448
  _Float16* vt_s  = smem + 8448;             // kt: 256*VSTRIDE = 10240
  _Float16* p_s   = smem + 18688;            // kt: 8 waves * 16*VSTRIDE = 5120
  _Float16* qw_hi = smem;                    // prologue: 256*VSTRIDE = 10240
  _Float16* qw_lo = smem + 10240;            // prologue: 10240
  _Float16* bo_hi = smem + 20480;            // prologue: 128*VSTRIDE = 5120
  _Float16* bo_lo = smem + 25600;            // prologue: 5120
  _Float16* qtb   = smem;                    // transpose: 128*QTSTRIDE = 17408
  const int tid = threadIdx.x, w = tid >> 6, lane = tid & 63;
  const int quad = lane >> 4, l15 = lane & 15;
  // natural mapping (R6 best-measured; R20 remap cost ~2%)
  const int hb = blockIdx.y, h = h0 + (hb >> 3), b = hb & 7;
  const int qbase = blockIdx.x * 128;  // block owns 128 q-rows; wave w owns rows w*16..+15

  // ---- fused q projection: qacc[df] = (bo rows w*16+l15) x (Qw^T), all 256 d ----
  const f32x4 fz = {0.f, 0.f, 0.f, 0.f};
  f32x4 qacc[16];
#pragma unroll
  for (int df = 0; df < 16; ++df) qacc[df] = fz;
  for (int kk = 0; kk < 8; ++kk) {
    __syncthreads();
    // stage Qw^T hi/lo: [256 d][32 f], 2 half8/thread each
#pragma unroll
    for (int i = 0; i < 2; ++i) {
      int c = i * 512 + tid;
      int dr = c >> 2, ch = (c & 3) * 8;
      size_t woff = ((size_t)h * 256 + dr) * 256 + kk * 32 + ch;
      *(half8*)&qw_hi[dr * VSTRIDE + ch] = *(const half8*)(qwhi + woff);
      *(half8*)&qw_lo[dr * VSTRIDE + ch] = *(const half8*)(qwlo + woff);
    }
    // stage bo hi/lo: [128 s][32 f], 1 split8/thread
    {
      int rrow = tid >> 2, ch = (tid & 3) * 8;
      half8 hv, lv;
      split8(bo + ((size_t)b * S_ + qbase + rrow) * 256 + kk * 32 + ch, hv, lv);
      *(half8*)&bo_hi[rrow * VSTRIDE + ch] = hv;
      *(half8*)&bo_lo[rrow * VSTRIDE + ch] = lv;
    }
    __syncthreads();
    half8 bh = *(const half8*)&bo_hi[(w * 16 + l15) * VSTRIDE + quad * 8];
    half8 bl = *(const half8*)&bo_lo[(w * 16 + l15) * VSTRIDE + quad * 8];
#pragma unroll
    for (int df = 0; df < 16; ++df) {
      half8 awh = *(const half8*)&qw_hi[(df * 16 + l15) * VSTRIDE + quad * 8];
      half8 awl = *(const half8*)&qw_lo[(df * 16 + l15) * VSTRIDE + quad * 8];
      // order matches proj<0>: a_hi*w_hi, a_hi*w_lo, a_lo*w_hi
      qacc[df] = __builtin_amdgcn_mfma_f32_16x16x32_f16(awh, bh, qacc[df], 0, 0, 0);
      qacc[df] = __builtin_amdgcn_mfma_f32_16x16x32_f16(awl, bh, qacc[df], 0, 0, 0);
      qacc[df] = __builtin_amdgcn_mfma_f32_16x16x32_f16(awh, bl, qacc[df], 0, 0, 0);
    }
  }
  // ---- bias + scale + hi/lo split + 4-phase LDS transpose into qfh/qfl ----
  // dh-major phase order (hi,lo per d-half) so qacc[0..7] dies before qfh/qfl[4..7] fill.
  half8 qfh[8], qfl[8];
#pragma unroll
  for (int ph = 0; ph < 4; ++ph) {
    const int dh = ph >> 1;        // which 128-d half
    const bool lo = ph & 1;
    __syncthreads();
#pragma unroll
    for (int dfi = 0; dfi < 8; ++dfi) {
      int df = dh * 8 + dfi;
#pragma unroll
      for (int rp = 0; rp < 2; ++rp) {
        half2v hw;
#pragma unroll
        for (int rr2 = 0; rr2 < 2; ++rr2) {
          int r = rp * 2 + rr2;
          float bv = qbias[h * 256 + df * 16 + quad * 4 + r];
          float val = (qacc[df][r] + bv) * 0.0625f;  // softmax 1/16 folded in
          _Float16 hv = (_Float16)val;
          hw[rr2] = lo ? (_Float16)(val - (float)hv) : hv;
        }
        *(half2v*)&qtb[(w * 16 + l15) * QTSTRIDE + dfi * 16 + quad * 4 + rp * 2] = hw;
      }
    }
    __syncthreads();
#pragma unroll
    for (int k2 = 0; k2 < 4; ++k2) {
      half8 v = *(const half8*)&qtb[(w * 16 + l15) * QTSTRIDE + k2 * 32 + quad * 8];
      if (lo) qfl[dh * 4 + k2] = v;
      else    qfh[dh * 4 + k2] = v;
    }
  }

  // ---- kt-loop: per-wave byte-identical to R1 ----
  f32x4 o_acc[16];
#pragma unroll
  for (int df = 0; df < 16; ++df) o_acc[df] = fz;
  float m_r = -3.0e38f, l_r = 0.f;
  _Float16* psw = p_s + w * (16 * VSTRIDE);

  for (int kt = 0; kt < 64; ++kt) {
    __syncthreads();  // prior iteration's PV reads of k/v LDS are done
    {
      size_t kbase = ((size_t)hb * S_ + kt * 32) * 256;
#pragma unroll
      for (int i = 0; i < 2; ++i) {
        int cc = i * 512 + tid;
        int kr = cc >> 5, kch = (cc & 31) * 8;
        *(half8*)&khi_s[kr * KSTRIDE + kch] = *(const half8*)(khi + kbase + kr * 256 + kch);
        int vd = cc >> 2, vch = (cc & 3) * 8;
        size_t voff = ((size_t)hb * 256 + vd) * S_ + kt * 32 + vch;
        *(half8*)&vt_s[vd * VSTRIDE + vch] = *(const half8*)(vt + voff);
      }
    }
    __syncthreads();
    // QK^T swapped: A = K-frag, B = Q-frag. C: row = quad*4+r = k-col, col = l15 = q.
    f32x4 sc0 = fz, sc1 = fz;
#pragma unroll
    for (int ks = 0; ks < 8; ++ks) {
      half8 bh0 = *(const half8*)&khi_s[(0 * 16 + l15) * KSTRIDE + ks * 32 + quad * 8];
      sc0 = __builtin_amdgcn_mfma_f32_16x16x32_f16(bh0, qfh[ks], sc0, 0, 0, 0);
      sc0 = __builtin_amdgcn_mfma_f32_16x16x32_f16(bh0, qfl[ks], sc0, 0, 0, 0);
      half8 bh1 = *(const half8*)&khi_s[(1 * 16 + l15) * KSTRIDE + ks * 32 + quad * 8];
      sc1 = __builtin_amdgcn_mfma_f32_16x16x32_f16(bh1, qfh[ks], sc1, 0, 0, 0);
      sc1 = __builtin_amdgcn_mfma_f32_16x16x32_f16(bh1, qfl[ks], sc1, 0, 0, 0);
    }
    // online softmax, in-register: lane owns q-row l15; 2 cross-quad shfls.
    float v = fmaxf(fmaxf(fmaxf(sc0[0], sc0[1]), fmaxf(sc0[2], sc0[3])),
                    fmaxf(fmaxf(sc1[0], sc1[1]), fmaxf(sc1[2], sc1[3])));
    v = fmaxf(v, __shfl_xor(v, 16));
    v = fmaxf(v, __shfl_xor(v, 32));
    const float mn = fmaxf(m_r, v);
    const float al = __expf(m_r - mn);
    m_r = mn;
    float p0[4], p1[4], s = 0.f;
#pragma unroll
    for (int r = 0; r < 4; ++r) {
      p0[r] = __expf(sc0[r] - mn);
      p1[r] = __expf(sc1[r] - mn);
      s += p0[r] + p1[r];
    }
    s += __shfl_xor(s, 16);
    s += __shfl_xor(s, 32);
    l_r = l_r * al + s;
    // P -> LDS: psw[q=l15][k=quad*4+r (+16 for tile1)], packed half2 stores
    {
      _Float16* pb = &psw[l15 * VSTRIDE + quad * 4];
      half2v w0 = {(_Float16)p0[0], (_Float16)p0[1]};
      half2v w1 = {(_Float16)p0[2], (_Float16)p0[3]};
      half2v w2 = {(_Float16)p1[0], (_Float16)p1[1]};
      half2v w3 = {(_Float16)p1[2], (_Float16)p1[3]};
      *(half2v*)(pb) = w0;
      *(half2v*)(pb + 2) = w1;
      *(half2v*)(pb + 16) = w2;
      *(half2v*)(pb + 18) = w3;
    }
    // rescale O accumulator: gather al for o-rows quad*4+r (held at lane l15==row)
    float al_r[4];
#pragma unroll
    for (int r = 0; r < 4; ++r) al_r[r] = __shfl(al, quad * 4 + r);
#pragma unroll
    for (int df = 0; df < 16; ++df)
#pragma unroll
      for (int r = 0; r < 4; ++r) o_acc[df][r] *= al_r[r];
    __syncthreads();  // phase barrier: keeps softmax and PV LDS phases aligned
    // PV: P in A-layout from LDS, V^T as B operand
    half8 pf = *(const half8*)&psw[l15 * VSTRIDE + quad * 8];
#pragma unroll
    for (int df = 0; df < 16; ++df) {
      half8 vf = *(const half8*)&vt_s[(df * 16 + l15) * VSTRIDE + quad * 8];
      o_acc[df] = __builtin_amdgcn_mfma_f32_16x16x32_f16(pf, vf, o_acc[df], 0, 0, 0);
    }
  }
  // epilogue: normalize + fused C-projection out[b,s,j] += sum_d o*Cw
  float rcl[4];
#pragma unroll
  for (int r = 0; r < 4; ++r) rcl[r] = 1.0f / __shfl(l_r, quad * 4 + r);
  float part[32];
#pragma unroll
  for (int i = 0; i < 32; ++i) part[i] = 0.f;
#pragma unroll
  for (int df = 0; df < 16; ++df) {
    const float4* cwv = (const float4*)(Cw + ((size_t)h * 256 + df * 16 + l15) * 8);
    float4 c0 = cwv[0], c1 = cwv[1];
#pragma unroll
    for (int r = 0; r < 4; ++r) {
      float ov = o_acc[df][r] * rcl[r];
      part[r * 8 + 0] += ov * c0.x;
      part[r * 8 + 1] += ov * c0.y;
      part[r * 8 + 2] += ov * c0.z;
      part[r * 8 + 3] += ov * c0.w;
      part[r * 8 + 4] += ov * c1.x;
      part[r * 8 + 5] += ov * c1.y;
      part[r * 8 + 6] += ov * c1.z;
      part[r * 8 + 7] += ov * c1.w;
    }
  }
#pragma unroll
  for (int i = 0; i < 32; ++i) {
    float v = part[i];
    v += __shfl_xor(v, 1);
    v += __shfl_xor(v, 2);
    v += __shfl_xor(v, 4);
    v += __shfl_xor(v, 8);
    part[i] = v;
  }
  if (l15 == 0) {
#pragma unroll
    for (int r = 0; r < 4; ++r) {
      int s = qbase + w * 16 + quad * 4 + r;
#pragma unroll
      for (int j = 0; j < 8; ++j)
        atomicAdd(&out[((size_t)b * S_ + s) * 8 + j], part[r * 8 + j]);
    }
  }
}

extern "C" void kernel_launch(void* const* d_in, const int* in_sizes, int n_in,
                              void* d_out, int out_size, void* d_ws, size_t ws_size,
                              hipStream_t stream) {
  const float* x  = (const float*)d_in[0];
  const float* bo = (const float*)d_in[1];
  const float* Qw = (const float*)d_in[2];
  const float* Qb = (const float*)d_in[3];
  const float* Kw = (const float*)d_in[4];
  const float* Kb = (const float*)d_in[5];
  const float* Vw = (const float*)d_in[6];
  const float* Vb = (const float*)d_in[7];
  const float* Cw = (const float*)d_in[8];
  const float* Cb = (const float*)d_in[9];
  float* out = (float*)d_out;

  const size_t NW  = (size_t)H_ * 256 * 256;
  const size_t NHB = (size_t)B_ * S_ * 256;
  const size_t ALN = 256;
  auto pad = [](size_t b) { return (b + 255) & ~(size_t)255; };

  // pick largest head-chunk HC in {8,4,2,1} whose scratch fits ws_size
  // (q hi/lo no longer materialized — only k_hi and v_t chunks)
  int HC = 8;
  while (HC > 1) {
    size_t need = 6 * pad(NW * 2) + 2 * pad((size_t)HC * NHB * 2) + ALN;
    if (need <= ws_size) break;
    HC >>= 1;
  }

  char* base = (char*)d_ws;
  size_t off = 0;
  auto carve = [&](size_t nelem) -> _Float16* {
    _Float16* p = (_Float16*)(base + off);
    off += pad(nelem * 2);
    return p;
  };
  _Float16* qwt_hi = carve(NW); _Float16* qwt_lo = carve(NW);
  _Float16* kwt_hi = carve(NW); _Float16* kwt_lo = carve(NW);
  _Float16* vwt_hi = carve(NW); _Float16* vwt_lo = carve(NW);
  const size_t NC = (size_t)HC * NHB;
  _Float16* k_hi = carve(NC);
  _Float16* v_t  = carve(NC);

  dim3 wg(4, 4, 8);
  split_w_kernel<<<wg, 256, 0, stream>>>(Qw, qwt_hi, qwt_lo);
  split_w_kernel<<<wg, 256, 0, stream>>>(Kw, kwt_hi, kwt_lo);
  split_w_kernel<<<wg, 256, 0, stream>>>(Vw, vwt_hi, vwt_lo);
  out_init_kernel<<<(B_ * S_ * 8) / 256, 256, 0, stream>>>(out, Cb);

  for (int h0 = 0; h0 < H_; h0 += HC) {
    dim3 pg(16, 2, HC * 8);
    proj_kernel<2><<<pg, 256, 0, stream>>>(x, kwt_hi, kwt_lo, Kb, 1.0f, h0, k_hi, nullptr);
    proj_kernel<1><<<pg, 256, 0, stream>>>(x, vwt_hi, vwt_lo, Vb, 1.0f, h0, v_t, nullptr);
    dim3 fg(16, HC * 8);
    flash_kernel<<<fg, 512, 0, stream>>>(bo, qwt_hi, qwt_lo, Qb, k_hi, v_t, Cw, out, h0);
  }
}

// Round 10
// 850.893 us; speedup vs baseline: 1.6162x; 1.0403x over previous
//
#include <hip/hip_runtime.h>

#define H_ 8
#define B_ 8
#define S_ 2048
#define D_ 256

// padded LDS strides (halves): kill 8/16-way bank conflicts, keep 16B alignment
#define KSTRIDE 264   // k-tile rows: 528B = 4 banks offset/row
#define VSTRIDE 40    // 32-col tiles: 80B = 20 banks offset/row
#define QTSTRIDE 136  // q-transpose rows: 128 d + pad, 272B = 16B-aligned

typedef __attribute__((ext_vector_type(8))) _Float16 half8;
typedef __attribute__((ext_vector_type(4))) _Float16 half4v;
typedef __attribute__((ext_vector_type(2))) _Float16 half2v;
typedef __attribute__((ext_vector_type(4))) float f32x4;

// split 8 consecutive fp32 into fp16 hi + lo residual
__device__ inline void split8(const float* __restrict__ p, half8& hv, half8& lv) {
  float4 a = *(const float4*)p, b = *(const float4*)(p + 4);
  hv[0] = (_Float16)a.x; hv[1] = (_Float16)a.y; hv[2] = (_Float16)a.z; hv[3] = (_Float16)a.w;
  hv[4] = (_Float16)b.x; hv[5] = (_Float16)b.y; hv[6] = (_Float16)b.z; hv[7] = (_Float16)b.w;
  lv[0] = (_Float16)(a.x - (float)hv[0]); lv[1] = (_Float16)(a.y - (float)hv[1]);
  lv[2] = (_Float16)(a.z - (float)hv[2]); lv[3] = (_Float16)(a.w - (float)hv[3]);
  lv[4] = (_Float16)(b.x - (float)hv[4]); lv[5] = (_Float16)(b.y - (float)hv[5]);
  lv[6] = (_Float16)(b.z - (float)hv[6]); lv[7] = (_Float16)(b.w - (float)hv[7]);
}

// ------- transpose + split weights via LDS tile: W[h][f][d] -> Wt hi/lo [h][d][f] -------
__global__ void split_w_kernel(const float* __restrict__ W,
                               _Float16* __restrict__ thi, _Float16* __restrict__ tlo) {
  __shared__ float t[64][65];
  const int h = blockIdx.z, f0 = blockIdx.x * 64, d0 = blockIdx.y * 64;
  const int col = threadIdx.x & 63, rg = threadIdx.x >> 6;
#pragma unroll
  for (int it = 0; it < 16; ++it) {
    int f = rg * 16 + it;
    t[f][col] = W[((size_t)h * 256 + f0 + f) * 256 + d0 + col];
  }
  __syncthreads();
#pragma unroll
  for (int it = 0; it < 16; ++it) {
    int d = rg * 16 + it;
    float v = t[col][d];
    _Float16 hv = (_Float16)v;
    size_t idx = ((size_t)h * 256 + d0 + d) * 256 + f0 + col;
    thi[idx] = hv;
    tlo[idx] = (_Float16)(v - (float)hv);
  }
}

// ---------------- out = Cb broadcast ----------------
__global__ void out_init_kernel(float* __restrict__ out, const float* __restrict__ Cb) {
  int i = blockIdx.x * blockDim.x + threadIdx.x;
  if (i < B_ * S_ * 8) out[i] = Cb[i & 7];
}

// ---- projection GEMM (R10's best-measured config — FROZEN) ----
// Used for K (VMODE 2) and V (VMODE 1) only; q-proj is fused into flash (R19).
template <int VMODE>
__global__ __launch_bounds__(256, 2) void proj_kernel(
    const float* __restrict__ A,
    const _Float16* __restrict__ Whi, const _Float16* __restrict__ Wlo,
    const float* __restrict__ bias, float oscale, int h0,
    _Float16* __restrict__ Ohi, _Float16* __restrict__ Olo) {
  constexpr bool TMULT = (VMODE != 1);
  __shared__ _Float16 a_hi[128 * VSTRIDE] __attribute__((aligned(16)));
  __shared__ _Float16 b_hi[128 * VSTRIDE] __attribute__((aligned(16)));
  __shared__ _Float16 a_lo[TMULT ? 128 * VSTRIDE : 8] __attribute__((aligned(16)));
  __shared__ _Float16 b_lo[TMULT ? 128 * VSTRIDE : 8] __attribute__((aligned(16)));
  const int tid = threadIdx.x;
  const int w = tid >> 6, lane = tid & 63;
  const int quad = lane >> 4, l15 = lane & 15;
  const int hb = blockIdx.z, h = h0 + (hb >> 3), b = hb & 7;
  const int s0 = blockIdx.x * 128, d0 = blockIdx.y * 128;
  const int wr = w >> 1, wc = w & 1;
  const f32x4 fz = {0.f, 0.f, 0.f, 0.f};
  f32x4 acc[4][4];
#pragma unroll
  for (int i = 0; i < 4; ++i)
#pragma unroll
    for (int j = 0; j < 4; ++j) acc[i][j] = fz;
  const size_t arow0 = (size_t)b * S_ + s0;
  const size_t wrow0 = (size_t)h * 256 + d0;
  for (int kk = 0; kk < 8; ++kk) {
    const int f0 = kk * 32;
    __syncthreads();
#pragma unroll
    for (int i = 0; i < 2; ++i) {
      int cc = i * 256 + tid;
      int r = cc >> 2, ch = (cc & 3) * 8;
      half8 hv, lv;
      split8(A + (arow0 + r) * 256 + f0 + ch, hv, lv);
      *(half8*)&a_hi[r * VSTRIDE + ch] = hv;
      size_t woff = (wrow0 + r) * 256 + f0 + ch;
      *(half8*)&b_hi[r * VSTRIDE + ch] = *(const half8*)(Whi + woff);
      if (TMULT) {
        *(half8*)&a_lo[r * VSTRIDE + ch] = lv;
        *(half8*)&b_lo[r * VSTRIDE + ch] = *(const half8*)(Wlo + woff);
      }
    }
    __syncthreads();
    half8 afh[4], afl[4], bfh[4], bfl[4];
#pragma unroll
    for (int t = 0; t < 4; ++t) {
      int ar = wr * 64 + t * 16 + l15;
      afh[t] = *(const half8*)&a_hi[ar * VSTRIDE + quad * 8];
      int br = wc * 64 + t * 16 + l15;
      bfh[t] = *(const half8*)&b_hi[br * VSTRIDE + quad * 8];
      if (TMULT) {
        afl[t] = *(const half8*)&a_lo[ar * VSTRIDE + quad * 8];
        bfl[t] = *(const half8*)&b_lo[br * VSTRIDE + quad * 8];
      }
    }
#pragma unroll
    for (int rf = 0; rf < 4; ++rf)
#pragma unroll
      for (int cf = 0; cf < 4; ++cf) {
        acc[rf][cf] = __builtin_amdgcn_mfma_f32_16x16x32_f16(afh[rf], bfh[cf], acc[rf][cf], 0, 0, 0);
        if (TMULT) {
          acc[rf][cf] = __builtin_amdgcn_mfma_f32_16x16x32_f16(afh[rf], bfl[cf], acc[rf][cf], 0, 0, 0);
          acc[rf][cf] = __builtin_amdgcn_mfma_f32_16x16x32_f16(afl[rf], bfh[cf], acc[rf][cf], 0, 0, 0);
        }
      }
  }
  // epilogue: C/D layout row = quad*4+reg (s), col = lane&15 (d)
#pragma unroll
  for (int rf = 0; rf < 4; ++rf) {
#pragma unroll
    for (int cf = 0; cf < 4; ++cf) {
      const int d = d0 + wc * 64 + cf * 16 + l15;
      const float bv = bias[h * 256 + d];
      if (VMODE != 1) {
#pragma unroll
        for (int r = 0; r < 4; ++r) {
          const int s = s0 + wr * 64 + rf * 16 + quad * 4 + r;
          float val = (acc[rf][cf][r] + bv) * oscale;
          _Float16 hvv = (_Float16)val;
          size_t idx = ((size_t)hb * S_ + s) * 256 + d;
          Ohi[idx] = hvv;
          if (VMODE == 0) Olo[idx] = (_Float16)(val - (float)hvv);
        }
      } else {
        // lane holds 4 consecutive s for fixed d -> coalesced half4 store along S
        half4v pack;
#pragma unroll
        for (int r = 0; r < 4; ++r) pack[r] = (_Float16)((acc[rf][cf][r] + bv) * oscale);
        size_t idx = ((size_t)hb * 256 + d) * S_ + s0 + wr * 64 + rf * 16 + quad * 4;
        *(half4v*)(Ohi + idx) = pack;
      }
    }
  }
}

// ---------------- flash attention + fused Q-projection + fused C-projection ----------------
// R19: q-proj fused as prologue (net -82us vs separate proj_q). R20 head-pinning: null.
// R21/R22 (512-thr): spills / -7% from 1 blk/CU — reverted to R6 shape (best, 837us).
// R23 (this round): prologue latency fix. Evidence: R9 halved Qw re-reads, FETCH moved
// only -25MB -> Qw re-reads are L2 hits; prologue's ~400us is LATENCY-bound (proj's
// documented disease: 8 x {stage->bar->mfma->bar} with ~240 MFMA-cyc vs ~500-900-cyc
// load chains). Fixes, inside the R6 shape:
//  1. bo loaded ONCE to registers (B-frags bfh/bfl, 32 VGPR) — deletes per-kk bo
//     staging + its LDS round-trip from the dependency chain.
//  2. Qw staged via register double-buffer (T14): kk+1 loads issued before kk's MFMAs,
//     L2/L3 latency hides under 48 MFMAs.
// MFMA operand order per kk unchanged -> numerics identical (absmax 56.0).
__global__ __launch_bounds__(256, 2) void flash_kernel(
    const float* __restrict__ bo,
    const _Float16* __restrict__ qwhi, const _Float16* __restrict__ qwlo,
    const float* __restrict__ qbias,
    const _Float16* __restrict__ khi,
    const _Float16* __restrict__ vt, const float* __restrict__ Cw,
    float* __restrict__ out, int h0) {
  __shared__ _Float16 khi_s[32 * KSTRIDE] __attribute__((aligned(16)));
  __shared__ _Float16 vt_s[256 * VSTRIDE] __attribute__((aligned(16)));
  __shared__ _Float16 p_s[4][16 * VSTRIDE] __attribute__((aligned(16)));
  __shared__ _Float16 wbuf[256 * VSTRIDE] __attribute__((aligned(16)));
  const int tid = threadIdx.x, w = tid >> 6, lane = tid & 63;
  const int quad = lane >> 4, l15 = lane & 15;
  const int hb = blockIdx.y, h = h0 + (hb >> 3), b = hb & 7;
  const int qbase = blockIdx.x * 64;

  // ---- bo rows -> registers ONCE: these ARE the prologue B-fragments ----
  half8 bfh[8], bfl[8];
  {
    const float* bop = bo + ((size_t)b * S_ + qbase + w * 16 + l15) * 256 + quad * 8;
#pragma unroll
    for (int kk = 0; kk < 8; ++kk) split8(bop + kk * 32, bfh[kk], bfl[kk]);
  }

  // ---- fused q projection: qacc[df] = (bo row) x (Qw^T), D[d][q=l15] ----
  const f32x4 fz = {0.f, 0.f, 0.f, 0.f};
  f32x4 qacc[16];
#pragma unroll
  for (int df = 0; df < 16; ++df) qacc[df] = fz;
  // Qw register double-buffer (T14 issue-early / write-late)
  half8 stH[4], stL[4];
  auto LOADW = [&](int kk) {
#pragma unroll
    for (int i = 0; i < 4; ++i) {
      int c = i * 256 + tid;
      int dr = c >> 2, ch = (c & 3) * 8;
      size_t woff = ((size_t)h * 256 + dr) * 256 + kk * 32 + ch;
      stH[i] = *(const half8*)(qwhi + woff);
      stL[i] = *(const half8*)(qwlo + woff);
    }
  };
  LOADW(0);
  for (int kk = 0; kk < 8; ++kk) {
    __syncthreads();  // prior step's LDS reads done
#pragma unroll
    for (int i = 0; i < 4; ++i) {
      int c = i * 256 + tid;
      int dr = c >> 2, ch = (c & 3) * 8;
      *(half8*)&vt_s[dr * VSTRIDE + ch] = stH[i];
      *(half8*)&wbuf[dr * VSTRIDE + ch] = stL[i];
    }
    __syncthreads();
    if (kk < 7) LOADW(kk + 1);  // next step's loads fly under this step's MFMAs
#pragma unroll
    for (int df = 0; df < 16; ++df) {
      half8 awh = *(const half8*)&vt_s[(df * 16 + l15) * VSTRIDE + quad * 8];
      half8 awl = *(const half8*)&wbuf[(df * 16 + l15) * VSTRIDE + quad * 8];
      // order matches proj<0>: a_hi*w_hi, a_hi*w_lo, a_lo*w_hi
      qacc[df] = __builtin_amdgcn_mfma_f32_16x16x32_f16(awh, bfh[kk], qacc[df], 0, 0, 0);
      qacc[df] = __builtin_amdgcn_mfma_f32_16x16x32_f16(awl, bfh[kk], qacc[df], 0, 0, 0);
      qacc[df] = __builtin_amdgcn_mfma_f32_16x16x32_f16(awh, bfl[kk], qacc[df], 0, 0, 0);
    }
  }
  // ---- bias + scale + hi/lo split + 4-phase LDS transpose into qfh/qfl ----
  // qacc layout: d = df*16 + quad*4 + r, q = l15. kt-loop needs q[row=l15][quad*8+ks*32].
  half8 qfh[8], qfl[8];
#pragma unroll
  for (int ph = 0; ph < 4; ++ph) {
    const int dh = ph >> 1;        // which 128-d half
    const bool lo = ph & 1;
    __syncthreads();
#pragma unroll
    for (int dfi = 0; dfi < 8; ++dfi) {
      int df = dh * 8 + dfi;
#pragma unroll
      for (int rp = 0; rp < 2; ++rp) {
        half2v hw;
#pragma unroll
        for (int rr2 = 0; rr2 < 2; ++rr2) {
          int r = rp * 2 + rr2;
          float bv = qbias[h * 256 + df * 16 + quad * 4 + r];
          float val = (qacc[df][r] + bv) * 0.0625f;  // softmax 1/16 folded in
          _Float16 hv = (_Float16)val;
          hw[rr2] = lo ? (_Float16)(val - (float)hv) : hv;
        }
        *(half2v*)&vt_s[(w * 16 + l15) * QTSTRIDE + dfi * 16 + quad * 4 + rp * 2] = hw;
      }
    }
    __syncthreads();
#pragma unroll
    for (int k2 = 0; k2 < 4; ++k2) {
      half8 v = *(const half8*)&vt_s[(w * 16 + l15) * QTSTRIDE + k2 * 32 + quad * 8];
      if (lo) qfl[dh * 4 + k2] = v;
      else    qfh[dh * 4 + k2] = v;
    }
  }

  // ---- kt-loop: byte-identical to R1/R6 ----
  f32x4 o_acc[16];
#pragma unroll
  for (int df = 0; df < 16; ++df) o_acc[df] = fz;
  float m_r = -3.0e38f, l_r = 0.f;

  for (int kt = 0; kt < 64; ++kt) {
    __syncthreads();  // prior iteration's PV reads of k/v LDS are done
    {
      size_t kbase = ((size_t)hb * S_ + kt * 32) * 256;
#pragma unroll
      for (int i = 0; i < 4; ++i) {
        int cc = i * 256 + tid;
        int kr = cc >> 5, kch = (cc & 31) * 8;
        *(half8*)&khi_s[kr * KSTRIDE + kch] = *(const half8*)(khi + kbase + kr * 256 + kch);
        int vd = cc >> 2, vch = (cc & 3) * 8;
        size_t voff = ((size_t)hb * 256 + vd) * S_ + kt * 32 + vch;
        *(half8*)&vt_s[vd * VSTRIDE + vch] = *(const half8*)(vt + voff);
      }
    }
    __syncthreads();
    // QK^T swapped: A = K-frag, B = Q-frag. C: row = quad*4+r = k-col, col = l15 = q.
    f32x4 sc0 = fz, sc1 = fz;
#pragma unroll
    for (int ks = 0; ks < 8; ++ks) {
      half8 bh0 = *(const half8*)&khi_s[(0 * 16 + l15) * KSTRIDE + ks * 32 + quad * 8];
      sc0 = __builtin_amdgcn_mfma_f32_16x16x32_f16(bh0, qfh[ks], sc0, 0, 0, 0);
      sc0 = __builtin_amdgcn_mfma_f32_16x16x32_f16(bh0, qfl[ks], sc0, 0, 0, 0);
      half8 bh1 = *(const half8*)&khi_s[(1 * 16 + l15) * KSTRIDE + ks * 32 + quad * 8];
      sc1 = __builtin_amdgcn_mfma_f32_16x16x32_f16(bh1, qfh[ks], sc1, 0, 0, 0);
      sc1 = __builtin_amdgcn_mfma_f32_16x16x32_f16(bh1, qfl[ks], sc1, 0, 0, 0);
    }
    // online softmax, in-register: lane owns q-row l15; 2 cross-quad shfls.
    float v = fmaxf(fmaxf(fmaxf(sc0[0], sc0[1]), fmaxf(sc0[2], sc0[3])),
                    fmaxf(fmaxf(sc1[0], sc1[1]), fmaxf(sc1[2], sc1[3])));
    v = fmaxf(v, __shfl_xor(v, 16));
    v = fmaxf(v, __shfl_xor(v, 32));
    const float mn = fmaxf(m_r, v);
    const float al = __expf(m_r - mn);
    m_r = mn;
    float p0[4], p1[4], s = 0.f;
#pragma unroll
    for (int r = 0; r < 4; ++r) {
      p0[r] = __expf(sc0[r] - mn);
      p1[r] = __expf(sc1[r] - mn);
      s += p0[r] + p1[r];
    }
    s += __shfl_xor(s, 16);
    s += __shfl_xor(s, 32);
    l_r = l_r * al + s;
    // P -> LDS: p_s[q=l15][k=quad*4+r (+16 for tile1)], packed half2 stores
    {
      _Float16* pb = &p_s[w][l15 * VSTRIDE + quad * 4];
      half2v w0 = {(_Float16)p0[0], (_Float16)p0[1]};
      half2v w1 = {(_Float16)p0[2], (_Float16)p0[3]};
      half2v w2 = {(_Float16)p1[0], (_Float16)p1[1]};
      half2v w3 = {(_Float16)p1[2], (_Float16)p1[3]};
      *(half2v*)(pb) = w0;
      *(half2v*)(pb + 2) = w1;
      *(half2v*)(pb + 16) = w2;
      *(half2v*)(pb + 18) = w3;
    }
    // rescale O accumulator: gather al for o-rows quad*4+r (held at lane l15==row)
    float al_r[4];
#pragma unroll
    for (int r = 0; r < 4; ++r) al_r[r] = __shfl(al, quad * 4 + r);
#pragma unroll
    for (int df = 0; df < 16; ++df)
#pragma unroll
      for (int r = 0; r < 4; ++r) o_acc[df][r] *= al_r[r];
    __syncthreads();  // phase barrier: keeps softmax and PV LDS phases aligned
    // PV: P in A-layout from LDS, V^T as B operand
    half8 pf = *(const half8*)&p_s[w][l15 * VSTRIDE + quad * 8];
#pragma unroll
    for (int df = 0; df < 16; ++df) {
      half8 vf = *(const half8*)&vt_s[(df * 16 + l15) * VSTRIDE + quad * 8];
      o_acc[df] = __builtin_amdgcn_mfma_f32_16x16x32_f16(pf, vf, o_acc[df], 0, 0, 0);
    }
  }
  // epilogue: normalize + fused C-projection out[b,s,j] += sum_d o*Cw
  float rcl[4];
#pragma unroll
  for (int r = 0; r < 4; ++r) rcl[r] = 1.0f / __shfl(l_r, quad * 4 + r);
  float part[32];
#pragma unroll
  for (int i = 0; i < 32; ++i) part[i] = 0.f;
#pragma unroll
  for (int df = 0; df < 16; ++df) {
    const float4* cwv = (const float4*)(Cw + ((size_t)h * 256 + df * 16 + l15) * 8);
    float4 c0 = cwv[0], c1 = cwv[1];
#pragma unroll
    for (int r = 0; r < 4; ++r) {
      float ov = o_acc[df][r] * rcl[r];
      part[r * 8 + 0] += ov * c0.x;
      part[r * 8 + 1] += ov * c0.y;
      part[r * 8 + 2] += ov * c0.z;
      part[r * 8 + 3] += ov * c0.w;
      part[r * 8 + 4] += ov * c1.x;
      part[r * 8 + 5] += ov * c1.y;
      part[r * 8 + 6] += ov * c1.z;
      part[r * 8 + 7] += ov * c1.w;
    }
  }
#pragma unroll
  for (int i = 0; i < 32; ++i) {
    float v = part[i];
    v += __shfl_xor(v, 1);
    v += __shfl_xor(v, 2);
    v += __shfl_xor(v, 4);
    v += __shfl_xor(v, 8);
    part[i] = v;
  }
  if (l15 == 0) {
#pragma unroll
    for (int r = 0; r < 4; ++r) {
      int s = qbase + w * 16 + quad * 4 + r;
#pragma unroll
      for (int j = 0; j < 8; ++j)
        atomicAdd(&out[((size_t)b * S_ + s) * 8 + j], part[r * 8 + j]);
    }
  }
}

extern "C" void kernel_launch(void* const* d_in, const int* in_sizes, int n_in,
                              void* d_out, int out_size, void* d_ws, size_t ws_size,
                              hipStream_t stream) {
  const float* x  = (const float*)d_in[0];
  const float* bo = (const float*)d_in[1];
  const float* Qw = (const float*)d_in[2];
  const float* Qb = (const float*)d_in[3];
  const float* Kw = (const float*)d_in[4];
  const float* Kb = (const float*)d_in[5];
  const float* Vw = (const float*)d_in[6];
  const float* Vb = (const float*)d_in[7];
  const float* Cw = (const float*)d_in[8];
  const float* Cb = (const float*)d_in[9];
  float* out = (float*)d_out;

  const size_t NW  = (size_t)H_ * 256 * 256;
  const size_t NHB = (size_t)B_ * S_ * 256;
  const size_t ALN = 256;
  auto pad = [](size_t b) { return (b + 255) & ~(size_t)255; };

  // pick largest head-chunk HC in {8,4,2,1} whose scratch fits ws_size
  // (q hi/lo no longer materialized — only k_hi and v_t chunks)
  int HC = 8;
  while (HC > 1) {
    size_t need = 6 * pad(NW * 2) + 2 * pad((size_t)HC * NHB * 2) + ALN;
    if (need <= ws_size) break;
    HC >>= 1;
  }

  char* base = (char*)d_ws;
  size_t off = 0;
  auto carve = [&](size_t nelem) -> _Float16* {
    _Float16* p = (_Float16*)(base + off);
    off += pad(nelem * 2);
    return p;
  };
  _Float16* qwt_hi = carve(NW); _Float16* qwt_lo = carve(NW);
  _Float16* kwt_hi = carve(NW); _Float16* kwt_lo = carve(NW);
  _Float16* vwt_hi = carve(NW); _Float16* vwt_lo = carve(NW);
  const size_t NC = (size_t)HC * NHB;
  _Float16* k_hi = carve(NC);
  _Float16* v_t  = carve(NC);

  dim3 wg(4, 4, 8);
  split_w_kernel<<<wg, 256, 0, stream>>>(Qw, qwt_hi, qwt_lo);
  split_w_kernel<<<wg, 256, 0, stream>>>(Kw, kwt_hi, kwt_lo);
  split_w_kernel<<<wg, 256, 0, stream>>>(Vw, vwt_hi, vwt_lo);
  out_init_kernel<<<(B_ * S_ * 8) / 256, 256, 0, stream>>>(out, Cb);

  for (int h0 = 0; h0 < H_; h0 += HC) {
    dim3 pg(16, 2, HC * 8);
    proj_kernel<2><<<pg, 256, 0, stream>>>(x, kwt_hi, kwt_lo, Kb, 1.0f, h0, k_hi, nullptr);
    proj_kernel<1><<<pg, 256, 0, stream>>>(x, vwt_hi, vwt_lo, Vb, 1.0f, h0, v_t, nullptr);
    dim3 fg(32, HC * 8);
    flash_kernel<<<fg, 256, 0, stream>>>(bo, qwt_hi, qwt_lo, Qb, k_hi, v_t, Cw, out, h0);
  }
}

// Round 11
// 843.945 us; speedup vs baseline: 1.6295x; 1.0082x over previous
//
#include <hip/hip_runtime.h>

#define H_ 8
#define B_ 8
#define S_ 2048
#define D_ 256

// padded LDS strides (halves): kill 8/16-way bank conflicts, keep 16B alignment
#define KSTRIDE 264   // k-tile rows: 528B = 4 banks offset/row
#define VSTRIDE 40    // 32-col tiles: 80B = 20 banks offset/row
#define QTSTRIDE 136  // q-transpose rows: 128 d + pad, 272B = 16B-aligned

typedef __attribute__((ext_vector_type(8))) _Float16 half8;
typedef __attribute__((ext_vector_type(4))) _Float16 half4v;
typedef __attribute__((ext_vector_type(2))) _Float16 half2v;
typedef __attribute__((ext_vector_type(4))) float f32x4;

// split 8 consecutive fp32 into fp16 hi + lo residual
__device__ inline void split8(const float* __restrict__ p, half8& hv, half8& lv) {
  float4 a = *(const float4*)p, b = *(const float4*)(p + 4);
  hv[0] = (_Float16)a.x; hv[1] = (_Float16)a.y; hv[2] = (_Float16)a.z; hv[3] = (_Float16)a.w;
  hv[4] = (_Float16)b.x; hv[5] = (_Float16)b.y; hv[6] = (_Float16)b.z; hv[7] = (_Float16)b.w;
  lv[0] = (_Float16)(a.x - (float)hv[0]); lv[1] = (_Float16)(a.y - (float)hv[1]);
  lv[2] = (_Float16)(a.z - (float)hv[2]); lv[3] = (_Float16)(a.w - (float)hv[3]);
  lv[4] = (_Float16)(b.x - (float)hv[4]); lv[5] = (_Float16)(b.y - (float)hv[5]);
  lv[6] = (_Float16)(b.z - (float)hv[6]); lv[7] = (_Float16)(b.w - (float)hv[7]);
}

// ------- transpose + split weights via LDS tile: W[h][f][d] -> Wt hi/lo [h][d][f] -------
__global__ void split_w_kernel(const float* __restrict__ W,
                               _Float16* __restrict__ thi, _Float16* __restrict__ tlo) {
  __shared__ float t[64][65];
  const int h = blockIdx.z, f0 = blockIdx.x * 64, d0 = blockIdx.y * 64;
  const int col = threadIdx.x & 63, rg = threadIdx.x >> 6;
#pragma unroll
  for (int it = 0; it < 16; ++it) {
    int f = rg * 16 + it;
    t[f][col] = W[((size_t)h * 256 + f0 + f) * 256 + d0 + col];
  }
  __syncthreads();
#pragma unroll
  for (int it = 0; it < 16; ++it) {
    int d = rg * 16 + it;
    float v = t[col][d];
    _Float16 hv = (_Float16)v;
    size_t idx = ((size_t)h * 256 + d0 + d) * 256 + f0 + col;
    thi[idx] = hv;
    tlo[idx] = (_Float16)(v - (float)hv);
  }
}

// ---------------- out = Cb broadcast ----------------
__global__ void out_init_kernel(float* __restrict__ out, const float* __restrict__ Cb) {
  int i = blockIdx.x * blockDim.x + threadIdx.x;
  if (i < B_ * S_ * 8) out[i] = Cb[i & 7];
}

// ---- projection GEMM (FROZEN) — K (VMODE 2) and V (VMODE 1) only ----
template <int VMODE>
__global__ __launch_bounds__(256, 2) void proj_kernel(
    const float* __restrict__ A,
    const _Float16* __restrict__ Whi, const _Float16* __restrict__ Wlo,
    const float* __restrict__ bias, float oscale, int h0,
    _Float16* __restrict__ Ohi, _Float16* __restrict__ Olo) {
  constexpr bool TMULT = (VMODE != 1);
  __shared__ _Float16 a_hi[128 * VSTRIDE] __attribute__((aligned(16)));
  __shared__ _Float16 b_hi[128 * VSTRIDE] __attribute__((aligned(16)));
  __shared__ _Float16 a_lo[TMULT ? 128 * VSTRIDE : 8] __attribute__((aligned(16)));
  __shared__ _Float16 b_lo[TMULT ? 128 * VSTRIDE : 8] __attribute__((aligned(16)));
  const int tid = threadIdx.x;
  const int w = tid >> 6, lane = tid & 63;
  const int quad = lane >> 4, l15 = lane & 15;
  const int hb = blockIdx.z, h = h0 + (hb >> 3), b = hb & 7;
  const int s0 = blockIdx.x * 128, d0 = blockIdx.y * 128;
  const int wr = w >> 1, wc = w & 1;
  const f32x4 fz = {0.f, 0.f, 0.f, 0.f};
  f32x4 acc[4][4];
#pragma unroll
  for (int i = 0; i < 4; ++i)
#pragma unroll
    for (int j = 0; j < 4; ++j) acc[i][j] = fz;
  const size_t arow0 = (size_t)b * S_ + s0;
  const size_t wrow0 = (size_t)h * 256 + d0;
  for (int kk = 0; kk < 8; ++kk) {
    const int f0 = kk * 32;
    __syncthreads();
#pragma unroll
    for (int i = 0; i < 2; ++i) {
      int cc = i * 256 + tid;
      int r = cc >> 2, ch = (cc & 3) * 8;
      half8 hv, lv;
      split8(A + (arow0 + r) * 256 + f0 + ch, hv, lv);
      *(half8*)&a_hi[r * VSTRIDE + ch] = hv;
      size_t woff = (wrow0 + r) * 256 + f0 + ch;
      *(half8*)&b_hi[r * VSTRIDE + ch] = *(const half8*)(Whi + woff);
      if (TMULT) {
        *(half8*)&a_lo[r * VSTRIDE + ch] = lv;
        *(half8*)&b_lo[r * VSTRIDE + ch] = *(const half8*)(Wlo + woff);
      }
    }
    __syncthreads();
    half8 afh[4], afl[4], bfh[4], bfl[4];
#pragma unroll
    for (int t = 0; t < 4; ++t) {
      int ar = wr * 64 + t * 16 + l15;
      afh[t] = *(const half8*)&a_hi[ar * VSTRIDE + quad * 8];
      int br = wc * 64 + t * 16 + l15;
      bfh[t] = *(const half8*)&b_hi[br * VSTRIDE + quad * 8];
      if (TMULT) {
        afl[t] = *(const half8*)&a_lo[ar * VSTRIDE + quad * 8];
        bfl[t] = *(const half8*)&b_lo[br * VSTRIDE + quad * 8];
      }
    }
#pragma unroll
    for (int rf = 0; rf < 4; ++rf)
#pragma unroll
      for (int cf = 0; cf < 4; ++cf) {
        acc[rf][cf] = __builtin_amdgcn_mfma_f32_16x16x32_f16(afh[rf], bfh[cf], acc[rf][cf], 0, 0, 0);
        if (TMULT) {
          acc[rf][cf] = __builtin_amdgcn_mfma_f32_16x16x32_f16(afh[rf], bfl[cf], acc[rf][cf], 0, 0, 0);
          acc[rf][cf] = __builtin_amdgcn_mfma_f32_16x16x32_f16(afl[rf], bfh[cf], acc[rf][cf], 0, 0, 0);
        }
      }
  }
  // epilogue: C/D layout row = quad*4+reg (s), col = lane&15 (d)
#pragma unroll
  for (int rf = 0; rf < 4; ++rf) {
#pragma unroll
    for (int cf = 0; cf < 4; ++cf) {
      const int d = d0 + wc * 64 + cf * 16 + l15;
      const float bv = bias[h * 256 + d];
      if (VMODE != 1) {
#pragma unroll
        for (int r = 0; r < 4; ++r) {
          const int s = s0 + wr * 64 + rf * 16 + quad * 4 + r;
          float val = (acc[rf][cf][r] + bv) * oscale;
          _Float16 hvv = (_Float16)val;
          size_t idx = ((size_t)hb * S_ + s) * 256 + d;
          Ohi[idx] = hvv;
          if (VMODE == 0) Olo[idx] = (_Float16)(val - (float)hvv);
        }
      } else {
        // lane holds 4 consecutive s for fixed d -> coalesced half4 store along S
        half4v pack;
#pragma unroll
        for (int r = 0; r < 4; ++r) pack[r] = (_Float16)((acc[rf][cf][r] + bv) * oscale);
        size_t idx = ((size_t)hb * 256 + d) * S_ + s0 + wr * 64 + rf * 16 + quad * 4;
        *(half4v*)(Ohi + idx) = pack;
      }
    }
  }
}

// ---------------- flash attention + fused Q-projection + fused C-projection ----------------
// ACCOUNTING FIX (R24): rocprof _ord spacing shows R1-era ran HC=4 (2 flash dispatches
// of 337us = 674us kt-loop total); fused configs run HC=8 (one 742us dispatch). So
// flash = kt-loop ~674us + prologue ~80us. R7-R10's Qw/prologue theories chased the
// ~80us part — hence three nulls. The kt-loop is the target.
// R24: T14 reg-staging in the kt-loop. Old critical path per kt: barrier -> global
// load K/V (L2 200-900cyc, naked) -> LDS write -> barrier -> compute. New: kt+1's
// K/V loaded into 32 VGPRs right after barrier B (latency hides under ~2000cyc of
// QK/softmax/PV); staging phase between barriers becomes pure reg->LDS writes.
// Prologue/numerics byte-identical to R6 (best, 837us); absmax must stay 56.0.
__global__ __launch_bounds__(256, 2) void flash_kernel(
    const float* __restrict__ bo,
    const _Float16* __restrict__ qwhi, const _Float16* __restrict__ qwlo,
    const float* __restrict__ qbias,
    const _Float16* __restrict__ khi,
    const _Float16* __restrict__ vt, const float* __restrict__ Cw,
    float* __restrict__ out, int h0) {
  __shared__ _Float16 khi_s[32 * KSTRIDE] __attribute__((aligned(16)));
  __shared__ _Float16 vt_s[256 * VSTRIDE] __attribute__((aligned(16)));
  __shared__ _Float16 p_s[4][16 * VSTRIDE] __attribute__((aligned(16)));
  __shared__ _Float16 wbuf[256 * VSTRIDE] __attribute__((aligned(16)));
  const int tid = threadIdx.x, w = tid >> 6, lane = tid & 63;
  const int quad = lane >> 4, l15 = lane & 15;
  const int hb = blockIdx.y, h = h0 + (hb >> 3), b = hb & 7;
  const int qbase = blockIdx.x * 64;
  _Float16* psf = &p_s[0][0];  // flat view, 2560 halves

  // ---- fused q projection: qacc[df] = (bo row) x (Qw^T), D[d][q=l15] ----
  const f32x4 fz = {0.f, 0.f, 0.f, 0.f};
  f32x4 qacc[16];
#pragma unroll
  for (int df = 0; df < 16; ++df) qacc[df] = fz;
  for (int kk = 0; kk < 8; ++kk) {
    __syncthreads();
    // stage Qw^T hi -> vt_s, lo -> wbuf: [256 d][32 f], 4 half8/thread each
#pragma unroll
    for (int i = 0; i < 4; ++i) {
      int c = i * 256 + tid;
      int dr = c >> 2, ch = (c & 3) * 8;
      size_t woff = ((size_t)h * 256 + dr) * 256 + kk * 32 + ch;
      *(half8*)&vt_s[dr * VSTRIDE + ch] = *(const half8*)(qwhi + woff);
      *(half8*)&wbuf[dr * VSTRIDE + ch] = *(const half8*)(qwlo + woff);
    }
    // stage bo hi -> khi_s, lo -> psf: [64 s][32 f], 1 split8/thread
    {
      int rrow = tid >> 2, ch = (tid & 3) * 8;
      half8 hv, lv;
      split8(bo + ((size_t)b * S_ + qbase + rrow) * 256 + kk * 32 + ch, hv, lv);
      *(half8*)&khi_s[rrow * VSTRIDE + ch] = hv;
      *(half8*)&psf[rrow * VSTRIDE + ch] = lv;
    }
    __syncthreads();
    half8 bh = *(const half8*)&khi_s[(w * 16 + l15) * VSTRIDE + quad * 8];
    half8 bl = *(const half8*)&psf[(w * 16 + l15) * VSTRIDE + quad * 8];
#pragma unroll
    for (int df = 0; df < 16; ++df) {
      half8 awh = *(const half8*)&vt_s[(df * 16 + l15) * VSTRIDE + quad * 8];
      half8 awl = *(const half8*)&wbuf[(df * 16 + l15) * VSTRIDE + quad * 8];
      // order matches proj<0>: a_hi*w_hi, a_hi*w_lo, a_lo*w_hi
      qacc[df] = __builtin_amdgcn_mfma_f32_16x16x32_f16(awh, bh, qacc[df], 0, 0, 0);
      qacc[df] = __builtin_amdgcn_mfma_f32_16x16x32_f16(awl, bh, qacc[df], 0, 0, 0);
      qacc[df] = __builtin_amdgcn_mfma_f32_16x16x32_f16(awh, bl, qacc[df], 0, 0, 0);
    }
  }

  // ---- T14: issue kt=0's K/V loads now; latency hides under the q-transpose ----
  half8 stK[4], stV[4];
  auto LOADKV = [&](int kt) {
    size_t kbase = ((size_t)hb * S_ + (size_t)kt * 32) * 256;
#pragma unroll
    for (int i = 0; i < 4; ++i) {
      int cc = i * 256 + tid;
      int kr = cc >> 5, kch = (cc & 31) * 8;
      stK[i] = *(const half8*)(khi + kbase + kr * 256 + kch);
      int vd = cc >> 2, vch = (cc & 3) * 8;
      stV[i] = *(const half8*)(vt + ((size_t)hb * 256 + vd) * S_ + (size_t)kt * 32 + vch);
    }
  };
  LOADKV(0);

  // ---- bias + scale + hi/lo split + 4-phase LDS transpose into qfh/qfl ----
  // qacc layout: d = df*16 + quad*4 + r, q = l15. kt-loop needs q[row=l15][quad*8+ks*32].
  half8 qfh[8], qfl[8];
#pragma unroll
  for (int ph = 0; ph < 4; ++ph) {
    const int dh = ph >> 1;        // which 128-d half
    const bool lo = ph & 1;
    __syncthreads();
#pragma unroll
    for (int dfi = 0; dfi < 8; ++dfi) {
      int df = dh * 8 + dfi;
#pragma unroll
      for (int rp = 0; rp < 2; ++rp) {
        half2v hw;
#pragma unroll
        for (int rr2 = 0; rr2 < 2; ++rr2) {
          int r = rp * 2 + rr2;
          float bv = qbias[h * 256 + df * 16 + quad * 4 + r];
          float val = (qacc[df][r] + bv) * 0.0625f;  // softmax 1/16 folded in
          _Float16 hv = (_Float16)val;
          hw[rr2] = lo ? (_Float16)(val - (float)hv) : hv;
        }
        *(half2v*)&vt_s[(w * 16 + l15) * QTSTRIDE + dfi * 16 + quad * 4 + rp * 2] = hw;
      }
    }
    __syncthreads();
#pragma unroll
    for (int k2 = 0; k2 < 4; ++k2) {
      half8 v = *(const half8*)&vt_s[(w * 16 + l15) * QTSTRIDE + k2 * 32 + quad * 8];
      if (lo) qfl[dh * 4 + k2] = v;
      else    qfh[dh * 4 + k2] = v;
    }
  }

  // ---- kt-loop: R6 structure + T14 reg-staged K/V ----
  f32x4 o_acc[16];
#pragma unroll
  for (int df = 0; df < 16; ++df) o_acc[df] = fz;
  float m_r = -3.0e38f, l_r = 0.f;

  for (int kt = 0; kt < 64; ++kt) {
    __syncthreads();  // prior iteration's PV reads of k/v LDS are done
    // staging phase: pure reg->LDS writes (no memory latency between barriers)
#pragma unroll
    for (int i = 0; i < 4; ++i) {
      int cc = i * 256 + tid;
      int kr = cc >> 5, kch = (cc & 31) * 8;
      *(half8*)&khi_s[kr * KSTRIDE + kch] = stK[i];
      int vd = cc >> 2, vch = (cc & 3) * 8;
      *(half8*)&vt_s[vd * VSTRIDE + vch] = stV[i];
    }
    __syncthreads();
    if (kt < 63) LOADKV(kt + 1);  // kt+1 loads fly under this iteration's compute
    // QK^T swapped: A = K-frag, B = Q-frag. C: row = quad*4+r = k-col, col = l15 = q.
    f32x4 sc0 = fz, sc1 = fz;
#pragma unroll
    for (int ks = 0; ks < 8; ++ks) {
      half8 bh0 = *(const half8*)&khi_s[(0 * 16 + l15) * KSTRIDE + ks * 32 + quad * 8];
      sc0 = __builtin_amdgcn_mfma_f32_16x16x32_f16(bh0, qfh[ks], sc0, 0, 0, 0);
      sc0 = __builtin_amdgcn_mfma_f32_16x16x32_f16(bh0, qfl[ks], sc0, 0, 0, 0);
      half8 bh1 = *(const half8*)&khi_s[(1 * 16 + l15) * KSTRIDE + ks * 32 + quad * 8];
      sc1 = __builtin_amdgcn_mfma_f32_16x16x32_f16(bh1, qfh[ks], sc1, 0, 0, 0);
      sc1 = __builtin_amdgcn_mfma_f32_16x16x32_f16(bh1, qfl[ks], sc1, 0, 0, 0);
    }
    // online softmax, in-register: lane owns q-row l15; 2 cross-quad shfls.
    float v = fmaxf(fmaxf(fmaxf(sc0[0], sc0[1]), fmaxf(sc0[2], sc0[3])),
                    fmaxf(fmaxf(sc1[0], sc1[1]), fmaxf(sc1[2], sc1[3])));
    v = fmaxf(v, __shfl_xor(v, 16));
    v = fmaxf(v, __shfl_xor(v, 32));
    const float mn = fmaxf(m_r, v);
    const float al = __expf(m_r - mn);
    m_r = mn;
    float p0[4], p1[4], s = 0.f;
#pragma unroll
    for (int r = 0; r < 4; ++r) {
      p0[r] = __expf(sc0[r] - mn);
      p1[r] = __expf(sc1[r] - mn);
      s += p0[r] + p1[r];
    }
    s += __shfl_xor(s, 16);
    s += __shfl_xor(s, 32);
    l_r = l_r * al + s;
    // P -> LDS: p_s[q=l15][k=quad*4+r (+16 for tile1)], packed half2 stores
    {
      _Float16* pb = &p_s[w][l15 * VSTRIDE + quad * 4];
      half2v w0 = {(_Float16)p0[0], (_Float16)p0[1]};
      half2v w1 = {(_Float16)p0[2], (_Float16)p0[3]};
      half2v w2 = {(_Float16)p1[0], (_Float16)p1[1]};
      half2v w3 = {(_Float16)p1[2], (_Float16)p1[3]};
      *(half2v*)(pb) = w0;
      *(half2v*)(pb + 2) = w1;
      *(half2v*)(pb + 16) = w2;
      *(half2v*)(pb + 18) = w3;
    }
    // rescale O accumulator: gather al for o-rows quad*4+r (held at lane l15==row)
    float al_r[4];
#pragma unroll
    for (int r = 0; r < 4; ++r) al_r[r] = __shfl(al, quad * 4 + r);
#pragma unroll
    for (int df = 0; df < 16; ++df)
#pragma unroll
      for (int r = 0; r < 4; ++r) o_acc[df][r] *= al_r[r];
    __syncthreads();  // phase barrier: keeps softmax and PV LDS phases aligned
    // PV: P in A-layout from LDS, V^T as B operand
    half8 pf = *(const half8*)&p_s[w][l15 * VSTRIDE + quad * 8];
#pragma unroll
    for (int df = 0; df < 16; ++df) {
      half8 vf = *(const half8*)&vt_s[(df * 16 + l15) * VSTRIDE + quad * 8];
      o_acc[df] = __builtin_amdgcn_mfma_f32_16x16x32_f16(pf, vf, o_acc[df], 0, 0, 0);
    }
  }
  // epilogue: normalize + fused C-projection out[b,s,j] += sum_d o*Cw
  float rcl[4];
#pragma unroll
  for (int r = 0; r < 4; ++r) rcl[r] = 1.0f / __shfl(l_r, quad * 4 + r);
  float part[32];
#pragma unroll
  for (int i = 0; i < 32; ++i) part[i] = 0.f;
#pragma unroll
  for (int df = 0; df < 16; ++df) {
    const float4* cwv = (const float4*)(Cw + ((size_t)h * 256 + df * 16 + l15) * 8);
    float4 c0 = cwv[0], c1 = cwv[1];
#pragma unroll
    for (int r = 0; r < 4; ++r) {
      float ov = o_acc[df][r] * rcl[r];
      part[r * 8 + 0] += ov * c0.x;
      part[r * 8 + 1] += ov * c0.y;
      part[r * 8 + 2] += ov * c0.z;
      part[r * 8 + 3] += ov * c0.w;
      part[r * 8 + 4] += ov * c1.x;
      part[r * 8 + 5] += ov * c1.y;
      part[r * 8 + 6] += ov * c1.z;
      part[r * 8 + 7] += ov * c1.w;
    }
  }
#pragma unroll
  for (int i = 0; i < 32; ++i) {
    float v = part[i];
    v += __shfl_xor(v, 1);
    v += __shfl_xor(v, 2);
    v += __shfl_xor(v, 4);
    v += __shfl_xor(v, 8);
    part[i] = v;
  }
  if (l15 == 0) {
#pragma unroll
    for (int r = 0; r < 4; ++r) {
      int s = qbase + w * 16 + quad * 4 + r;
#pragma unroll
      for (int j = 0; j < 8; ++j)
        atomicAdd(&out[((size_t)b * S_ + s) * 8 + j], part[r * 8 + j]);
    }
  }
}

extern "C" void kernel_launch(void* const* d_in, const int* in_sizes, int n_in,
                              void* d_out, int out_size, void* d_ws, size_t ws_size,
                              hipStream_t stream) {
  const float* x  = (const float*)d_in[0];
  const float* bo = (const float*)d_in[1];
  const float* Qw = (const float*)d_in[2];
  const float* Qb = (const float*)d_in[3];
  const float* Kw = (const float*)d_in[4];
  const float* Kb = (const float*)d_in[5];
  const float* Vw = (const float*)d_in[6];
  const float* Vb = (const float*)d_in[7];
  const float* Cw = (const float*)d_in[8];
  const float* Cb = (const float*)d_in[9];
  float* out = (float*)d_out;

  const size_t NW  = (size_t)H_ * 256 * 256;
  const size_t NHB = (size_t)B_ * S_ * 256;
  const size_t ALN = 256;
  auto pad = [](size_t b) { return (b + 255) & ~(size_t)255; };

  // pick largest head-chunk HC in {8,4,2,1} whose scratch fits ws_size
  // (q hi/lo no longer materialized — only k_hi and v_t chunks)
  int HC = 8;
  while (HC > 1) {
    size_t need = 6 * pad(NW * 2) + 2 * pad((size_t)HC * NHB * 2) + ALN;
    if (need <= ws_size) break;
    HC >>= 1;
  }

  char* base = (char*)d_ws;
  size_t off = 0;
  auto carve = [&](size_t nelem) -> _Float16* {
    _Float16* p = (_Float16*)(base + off);
    off += pad(nelem * 2);
    return p;
  };
  _Float16* qwt_hi = carve(NW); _Float16* qwt_lo = carve(NW);
  _Float16* kwt_hi = carve(NW); _Float16* kwt_lo = carve(NW);
  _Float16* vwt_hi = carve(NW); _Float16* vwt_lo = carve(NW);
  const size_t NC = (size_t)HC * NHB;
  _Float16* k_hi = carve(NC);
  _Float16* v_t  = carve(NC);

  dim3 wg(4, 4, 8);
  split_w_kernel<<<wg, 256, 0, stream>>>(Qw, qwt_hi, qwt_lo);
  split_w_kernel<<<wg, 256, 0, stream>>>(Kw, kwt_hi, kwt_lo);
  split_w_kernel<<<wg, 256, 0, stream>>>(Vw, vwt_hi, vwt_lo);
  out_init_kernel<<<(B_ * S_ * 8) / 256, 256, 0, stream>>>(out, Cb);

  for (int h0 = 0; h0 < H_; h0 += HC) {
    dim3 pg(16, 2, HC * 8);
    proj_kernel<2><<<pg, 256, 0, stream>>>(x, kwt_hi, kwt_lo, Kb, 1.0f, h0, k_hi, nullptr);
    proj_kernel<1><<<pg, 256, 0, stream>>>(x, vwt_hi, vwt_lo, Vb, 1.0f, h0, v_t, nullptr);
    dim3 fg(32, HC * 8);
    flash_kernel<<<fg, 256, 0, stream>>>(bo, qwt_hi, qwt_lo, Qb, k_hi, v_t, Cw, out, h0);
  }
}

// Round 12
// 777.897 us; speedup vs baseline: 1.7678x; 1.0849x over previous
//
#include <hip/hip_runtime.h>

#define H_ 8
#define B_ 8
#define S_ 2048
#define D_ 256

// padded LDS strides (halves): kill 8/16-way bank conflicts, keep 16B alignment
#define KSTRIDE 264   // k-tile rows: 528B = 4 banks offset/row
#define VSTRIDE 40    // 32-col tiles: 80B = 20 banks offset/row
#define QTSTRIDE 136  // q-transpose rows: 128 d + pad, 272B = 16B-aligned

typedef __attribute__((ext_vector_type(8))) _Float16 half8;
typedef __attribute__((ext_vector_type(4))) _Float16 half4v;
typedef __attribute__((ext_vector_type(2))) _Float16 half2v;
typedef __attribute__((ext_vector_type(4))) float f32x4;

// split 8 consecutive fp32 into fp16 hi + lo residual
__device__ inline void split8(const float* __restrict__ p, half8& hv, half8& lv) {
  float4 a = *(const float4*)p, b = *(const float4*)(p + 4);
  hv[0] = (_Float16)a.x; hv[1] = (_Float16)a.y; hv[2] = (_Float16)a.z; hv[3] = (_Float16)a.w;
  hv[4] = (_Float16)b.x; hv[5] = (_Float16)b.y; hv[6] = (_Float16)b.z; hv[7] = (_Float16)b.w;
  lv[0] = (_Float16)(a.x - (float)hv[0]); lv[1] = (_Float16)(a.y - (float)hv[1]);
  lv[2] = (_Float16)(a.z - (float)hv[2]); lv[3] = (_Float16)(a.w - (float)hv[3]);
  lv[4] = (_Float16)(b.x - (float)hv[4]); lv[5] = (_Float16)(b.y - (float)hv[5]);
  lv[6] = (_Float16)(b.z - (float)hv[6]); lv[7] = (_Float16)(b.w - (float)hv[7]);
}

// ------- transpose + split weights via LDS tile: W[h][f][d] -> Wt hi/lo [h][d][f] -------
__global__ void split_w_kernel(const float* __restrict__ W,
                               _Float16* __restrict__ thi, _Float16* __restrict__ tlo) {
  __shared__ float t[64][65];
  const int h = blockIdx.z, f0 = blockIdx.x * 64, d0 = blockIdx.y * 64;
  const int col = threadIdx.x & 63, rg = threadIdx.x >> 6;
#pragma unroll
  for (int it = 0; it < 16; ++it) {
    int f = rg * 16 + it;
    t[f][col] = W[((size_t)h * 256 + f0 + f) * 256 + d0 + col];
  }
  __syncthreads();
#pragma unroll
  for (int it = 0; it < 16; ++it) {
    int d = rg * 16 + it;
    float v = t[col][d];
    _Float16 hv = (_Float16)v;
    size_t idx = ((size_t)h * 256 + d0 + d) * 256 + f0 + col;
    thi[idx] = hv;
    tlo[idx] = (_Float16)(v - (float)hv);
  }
}

// ---------------- out = Cb broadcast ----------------
__global__ void out_init_kernel(float* __restrict__ out, const float* __restrict__ Cb) {
  int i = blockIdx.x * blockDim.x + threadIdx.x;
  if (i < B_ * S_ * 8) out[i] = Cb[i & 7];
}

// ---- projection GEMM (FROZEN) — K (VMODE 2) and V (VMODE 1) only ----
template <int VMODE>
__global__ __launch_bounds__(256, 2) void proj_kernel(
    const float* __restrict__ A,
    const _Float16* __restrict__ Whi, const _Float16* __restrict__ Wlo,
    const float* __restrict__ bias, float oscale, int h0,
    _Float16* __restrict__ Ohi, _Float16* __restrict__ Olo) {
  constexpr bool TMULT = (VMODE != 1);
  __shared__ _Float16 a_hi[128 * VSTRIDE] __attribute__((aligned(16)));
  __shared__ _Float16 b_hi[128 * VSTRIDE] __attribute__((aligned(16)));
  __shared__ _Float16 a_lo[TMULT ? 128 * VSTRIDE : 8] __attribute__((aligned(16)));
  __shared__ _Float16 b_lo[TMULT ? 128 * VSTRIDE : 8] __attribute__((aligned(16)));
  const int tid = threadIdx.x;
  const int w = tid >> 6, lane = tid & 63;
  const int quad = lane >> 4, l15 = lane & 15;
  const int hb = blockIdx.z, h = h0 + (hb >> 3), b = hb & 7;
  const int s0 = blockIdx.x * 128, d0 = blockIdx.y * 128;
  const int wr = w >> 1, wc = w & 1;
  const f32x4 fz = {0.f, 0.f, 0.f, 0.f};
  f32x4 acc[4][4];
#pragma unroll
  for (int i = 0; i < 4; ++i)
#pragma unroll
    for (int j = 0; j < 4; ++j) acc[i][j] = fz;
  const size_t arow0 = (size_t)b * S_ + s0;
  const size_t wrow0 = (size_t)h * 256 + d0;
  for (int kk = 0; kk < 8; ++kk) {
    const int f0 = kk * 32;
    __syncthreads();
#pragma unroll
    for (int i = 0; i < 2; ++i) {
      int cc = i * 256 + tid;
      int r = cc >> 2, ch = (cc & 3) * 8;
      half8 hv, lv;
      split8(A + (arow0 + r) * 256 + f0 + ch, hv, lv);
      *(half8*)&a_hi[r * VSTRIDE + ch] = hv;
      size_t woff = (wrow0 + r) * 256 + f0 + ch;
      *(half8*)&b_hi[r * VSTRIDE + ch] = *(const half8*)(Whi + woff);
      if (TMULT) {
        *(half8*)&a_lo[r * VSTRIDE + ch] = lv;
        *(half8*)&b_lo[r * VSTRIDE + ch] = *(const half8*)(Wlo + woff);
      }
    }
    __syncthreads();
    half8 afh[4], afl[4], bfh[4], bfl[4];
#pragma unroll
    for (int t = 0; t < 4; ++t) {
      int ar = wr * 64 + t * 16 + l15;
      afh[t] = *(const half8*)&a_hi[ar * VSTRIDE + quad * 8];
      int br = wc * 64 + t * 16 + l15;
      bfh[t] = *(const half8*)&b_hi[br * VSTRIDE + quad * 8];
      if (TMULT) {
        afl[t] = *(const half8*)&a_lo[ar * VSTRIDE + quad * 8];
        bfl[t] = *(const half8*)&b_lo[br * VSTRIDE + quad * 8];
      }
    }
#pragma unroll
    for (int rf = 0; rf < 4; ++rf)
#pragma unroll
      for (int cf = 0; cf < 4; ++cf) {
        acc[rf][cf] = __builtin_amdgcn_mfma_f32_16x16x32_f16(afh[rf], bfh[cf], acc[rf][cf], 0, 0, 0);
        if (TMULT) {
          acc[rf][cf] = __builtin_amdgcn_mfma_f32_16x16x32_f16(afh[rf], bfl[cf], acc[rf][cf], 0, 0, 0);
          acc[rf][cf] = __builtin_amdgcn_mfma_f32_16x16x32_f16(afl[rf], bfh[cf], acc[rf][cf], 0, 0, 0);
        }
      }
  }
  // epilogue: C/D layout row = quad*4+reg (s), col = lane&15 (d)
#pragma unroll
  for (int rf = 0; rf < 4; ++rf) {
#pragma unroll
    for (int cf = 0; cf < 4; ++cf) {
      const int d = d0 + wc * 64 + cf * 16 + l15;
      const float bv = bias[h * 256 + d];
      if (VMODE != 1) {
#pragma unroll
        for (int r = 0; r < 4; ++r) {
          const int s = s0 + wr * 64 + rf * 16 + quad * 4 + r;
          float val = (acc[rf][cf][r] + bv) * oscale;
          _Float16 hvv = (_Float16)val;
          size_t idx = ((size_t)hb * S_ + s) * 256 + d;
          Ohi[idx] = hvv;
          if (VMODE == 0) Olo[idx] = (_Float16)(val - (float)hvv);
        }
      } else {
        // lane holds 4 consecutive s for fixed d -> coalesced half4 store along S
        half4v pack;
#pragma unroll
        for (int r = 0; r < 4; ++r) pack[r] = (_Float16)((acc[rf][cf][r] + bv) * oscale);
        size_t idx = ((size_t)hb * 256 + d) * S_ + s0 + wr * 64 + rf * 16 + quad * 4;
        *(half4v*)(Ohi + idx) = pack;
      }
    }
  }
}

// pack 2 f32 -> 2 f16 (round-nearest, same conversion as prior P stores)
__device__ inline unsigned int pack2(float a, float b) {
  half2v h; h[0] = (_Float16)a; h[1] = (_Float16)b;
  return __builtin_bit_cast(unsigned int, h);
}

// ---------------- flash attention + fused Q-projection + fused C-projection ----------------
// R24: T14 reg-staged kt K/V (742->726). R25 (this round): kill the phase-C barrier +
// P LDS round-trip. P's write/read were wave-private; the only reason for the round
// trip was the layout permutation C-layout[k=quad*4+r tiles] -> A-layout[k=quad*8+j].
// That permutation is a fixed 4-quad exchange: pack p0/p1 into 4 u32, pull via 8
// __shfl (ds_bpermute) from lanes ((quad&1)<<5)+l15 / +16, select by target quad.
// Deletes 64 full-block barriers + 5 LDS ops/wave/kt + 5KB LDS. (R5's "barrier
// load-bearing" removed the barrier while KEEPING the round-trip — not this change.)
// Plus T13 defer-max: skip o_acc rescale unless __any(vmax > m_r+8) (P bounded by
// e^8, f16-safe; passed absmax 56.0 in R3/R4). kt-loop now 2 barriers (both required).
__global__ __launch_bounds__(256, 2) void flash_kernel(
    const float* __restrict__ bo,
    const _Float16* __restrict__ qwhi, const _Float16* __restrict__ qwlo,
    const float* __restrict__ qbias,
    const _Float16* __restrict__ khi,
    const _Float16* __restrict__ vt, const float* __restrict__ Cw,
    float* __restrict__ out, int h0) {
  __shared__ _Float16 khi_s[32 * KSTRIDE] __attribute__((aligned(16)));
  __shared__ _Float16 vt_s[256 * VSTRIDE] __attribute__((aligned(16)));
  __shared__ _Float16 wbuf[256 * VSTRIDE] __attribute__((aligned(16)));
  const int tid = threadIdx.x, w = tid >> 6, lane = tid & 63;
  const int quad = lane >> 4, l15 = lane & 15;
  const int hb = blockIdx.y, h = h0 + (hb >> 3), b = hb & 7;
  const int qbase = blockIdx.x * 64;

  // ---- fused q projection: qacc[df] = (bo row) x (Qw^T), D[d][q=l15] ----
  const f32x4 fz = {0.f, 0.f, 0.f, 0.f};
  f32x4 qacc[16];
#pragma unroll
  for (int df = 0; df < 16; ++df) qacc[df] = fz;
  for (int kk = 0; kk < 8; ++kk) {
    __syncthreads();
    // stage Qw^T hi -> vt_s, lo -> wbuf: [256 d][32 f], 4 half8/thread each
#pragma unroll
    for (int i = 0; i < 4; ++i) {
      int c = i * 256 + tid;
      int dr = c >> 2, ch = (c & 3) * 8;
      size_t woff = ((size_t)h * 256 + dr) * 256 + kk * 32 + ch;
      *(half8*)&vt_s[dr * VSTRIDE + ch] = *(const half8*)(qwhi + woff);
      *(half8*)&wbuf[dr * VSTRIDE + ch] = *(const half8*)(qwlo + woff);
    }
    // stage bo hi -> khi_s[0:2560], lo -> khi_s[2560:5120]: [64 s][32 f]
    {
      int rrow = tid >> 2, ch = (tid & 3) * 8;
      half8 hv, lv;
      split8(bo + ((size_t)b * S_ + qbase + rrow) * 256 + kk * 32 + ch, hv, lv);
      *(half8*)&khi_s[rrow * VSTRIDE + ch] = hv;
      *(half8*)&khi_s[2560 + rrow * VSTRIDE + ch] = lv;
    }
    __syncthreads();
    half8 bh = *(const half8*)&khi_s[(w * 16 + l15) * VSTRIDE + quad * 8];
    half8 bl = *(const half8*)&khi_s[2560 + (w * 16 + l15) * VSTRIDE + quad * 8];
#pragma unroll
    for (int df = 0; df < 16; ++df) {
      half8 awh = *(const half8*)&vt_s[(df * 16 + l15) * VSTRIDE + quad * 8];
      half8 awl = *(const half8*)&wbuf[(df * 16 + l15) * VSTRIDE + quad * 8];
      // order matches proj<0>: a_hi*w_hi, a_hi*w_lo, a_lo*w_hi
      qacc[df] = __builtin_amdgcn_mfma_f32_16x16x32_f16(awh, bh, qacc[df], 0, 0, 0);
      qacc[df] = __builtin_amdgcn_mfma_f32_16x16x32_f16(awl, bh, qacc[df], 0, 0, 0);
      qacc[df] = __builtin_amdgcn_mfma_f32_16x16x32_f16(awh, bl, qacc[df], 0, 0, 0);
    }
  }

  // ---- T14: issue kt=0's K/V loads now; latency hides under the q-transpose ----
  half8 stK[4], stV[4];
  auto LOADKV = [&](int kt) {
    size_t kbase = ((size_t)hb * S_ + (size_t)kt * 32) * 256;
#pragma unroll
    for (int i = 0; i < 4; ++i) {
      int cc = i * 256 + tid;
      int kr = cc >> 5, kch = (cc & 31) * 8;
      stK[i] = *(const half8*)(khi + kbase + kr * 256 + kch);
      int vd = cc >> 2, vch = (cc & 3) * 8;
      stV[i] = *(const half8*)(vt + ((size_t)hb * 256 + vd) * S_ + (size_t)kt * 32 + vch);
    }
  };
  LOADKV(0);

  // ---- bias + scale + hi/lo split + 4-phase LDS transpose into qfh/qfl ----
  // qacc layout: d = df*16 + quad*4 + r, q = l15. kt-loop needs q[row=l15][quad*8+ks*32].
  half8 qfh[8], qfl[8];
#pragma unroll
  for (int ph = 0; ph < 4; ++ph) {
    const int dh = ph >> 1;        // which 128-d half
    const bool lo = ph & 1;
    __syncthreads();
#pragma unroll
    for (int dfi = 0; dfi < 8; ++dfi) {
      int df = dh * 8 + dfi;
#pragma unroll
      for (int rp = 0; rp < 2; ++rp) {
        half2v hw;
#pragma unroll
        for (int rr2 = 0; rr2 < 2; ++rr2) {
          int r = rp * 2 + rr2;
          float bv = qbias[h * 256 + df * 16 + quad * 4 + r];
          float val = (qacc[df][r] + bv) * 0.0625f;  // softmax 1/16 folded in
          _Float16 hv = (_Float16)val;
          hw[rr2] = lo ? (_Float16)(val - (float)hv) : hv;
        }
        *(half2v*)&vt_s[(w * 16 + l15) * QTSTRIDE + dfi * 16 + quad * 4 + rp * 2] = hw;
      }
    }
    __syncthreads();
#pragma unroll
    for (int k2 = 0; k2 < 4; ++k2) {
      half8 v = *(const half8*)&vt_s[(w * 16 + l15) * QTSTRIDE + k2 * 32 + quad * 8];
      if (lo) qfl[dh * 4 + k2] = v;
      else    qfh[dh * 4 + k2] = v;
    }
  }

  // ---- kt-loop: 2 barriers/iter, P stays in registers ----
  f32x4 o_acc[16];
#pragma unroll
  for (int df = 0; df < 16; ++df) o_acc[df] = fz;
  float m_r = -3.0e38f, l_r = 0.f;

  for (int kt = 0; kt < 64; ++kt) {
    __syncthreads();  // barrier A: prior iteration's LDS reads done
    // staging phase: pure reg->LDS writes (no memory latency between barriers)
#pragma unroll
    for (int i = 0; i < 4; ++i) {
      int cc = i * 256 + tid;
      int kr = cc >> 5, kch = (cc & 31) * 8;
      *(half8*)&khi_s[kr * KSTRIDE + kch] = stK[i];
      int vd = cc >> 2, vch = (cc & 3) * 8;
      *(half8*)&vt_s[vd * VSTRIDE + vch] = stV[i];
    }
    __syncthreads();  // barrier B: tile visible to all waves
    if (kt < 63) LOADKV(kt + 1);  // kt+1 loads fly under this iteration's compute
    // QK^T swapped: A = K-frag, B = Q-frag. C: row = quad*4+r = k-col, col = l15 = q.
    f32x4 sc0 = fz, sc1 = fz;
#pragma unroll
    for (int ks = 0; ks < 8; ++ks) {
      half8 bh0 = *(const half8*)&khi_s[(0 * 16 + l15) * KSTRIDE + ks * 32 + quad * 8];
      sc0 = __builtin_amdgcn_mfma_f32_16x16x32_f16(bh0, qfh[ks], sc0, 0, 0, 0);
      sc0 = __builtin_amdgcn_mfma_f32_16x16x32_f16(bh0, qfl[ks], sc0, 0, 0, 0);
      half8 bh1 = *(const half8*)&khi_s[(1 * 16 + l15) * KSTRIDE + ks * 32 + quad * 8];
      sc1 = __builtin_amdgcn_mfma_f32_16x16x32_f16(bh1, qfh[ks], sc1, 0, 0, 0);
      sc1 = __builtin_amdgcn_mfma_f32_16x16x32_f16(bh1, qfl[ks], sc1, 0, 0, 0);
    }
    // online softmax, in-register: lane owns q-row l15; 2 cross-quad shfls.
    float v = fmaxf(fmaxf(fmaxf(sc0[0], sc0[1]), fmaxf(sc0[2], sc0[3])),
                    fmaxf(fmaxf(sc1[0], sc1[1]), fmaxf(sc1[2], sc1[3])));
    v = fmaxf(v, __shfl_xor(v, 16));
    v = fmaxf(v, __shfl_xor(v, 32));
    // T13 defer-max: only rescale when some q's tile-max beats running max by >8
    if (__any(v > m_r + 8.0f)) {
      const float mn = fmaxf(m_r, v);
      const float al = __expf(m_r - mn);
      m_r = mn;
      l_r *= al;
      float al_r[4];
#pragma unroll
      for (int r = 0; r < 4; ++r) al_r[r] = __shfl(al, quad * 4 + r);
#pragma unroll
      for (int df = 0; df < 16; ++df)
#pragma unroll
        for (int r = 0; r < 4; ++r) o_acc[df][r] *= al_r[r];
    }
    float p0[4], p1[4], s = 0.f;
#pragma unroll
    for (int r = 0; r < 4; ++r) {
      p0[r] = __expf(sc0[r] - m_r);
      p1[r] = __expf(sc1[r] - m_r);
      s += p0[r] + p1[r];
    }
    s += __shfl_xor(s, 16);
    s += __shfl_xor(s, 32);
    l_r += s;
    // build PV A-frag in registers: lane (quad,l15) needs P[l15][quad*8+j], j=0..7.
    // own regs hold k=quad*4+r (p0) and 16+quad*4+r (p1); sources are quads
    // (2*quad)&3 and (2*quad+1)&3 at the same l15; select p0/p1 by target quad.
    {
      unsigned int u0 = pack2(p0[0], p0[1]), u1 = pack2(p0[2], p0[3]);
      unsigned int v0 = pack2(p1[0], p1[1]), v1 = pack2(p1[2], p1[3]);
      const int src0 = ((quad & 1) << 5) + l15;   // quads 0,2 -> lane l15; 1,3 -> 32+l15
      const int src1 = src0 + 16;
      unsigned int a0 = __shfl(u0, src0), a1 = __shfl(u1, src0);
      unsigned int a2 = __shfl(u0, src1), a3 = __shfl(u1, src1);
      unsigned int c0 = __shfl(v0, src0), c1 = __shfl(v1, src0);
      unsigned int c2 = __shfl(v0, src1), c3 = __shfl(v1, src1);
      union U { unsigned int u[4]; half8 h; } pu;
      const bool hiq = quad >= 2;
      pu.u[0] = hiq ? c0 : a0;
      pu.u[1] = hiq ? c1 : a1;
      pu.u[2] = hiq ? c2 : a2;
      pu.u[3] = hiq ? c3 : a3;
      half8 pf = pu.h;
      // PV: P in A-layout (registers), V^T as B operand — no barrier needed
#pragma unroll
      for (int df = 0; df < 16; ++df) {
        half8 vf = *(const half8*)&vt_s[(df * 16 + l15) * VSTRIDE + quad * 8];
        o_acc[df] = __builtin_amdgcn_mfma_f32_16x16x32_f16(pf, vf, o_acc[df], 0, 0, 0);
      }
    }
  }
  // epilogue: normalize + fused C-projection out[b,s,j] += sum_d o*Cw
  float rcl[4];
#pragma unroll
  for (int r = 0; r < 4; ++r) rcl[r] = 1.0f / __shfl(l_r, quad * 4 + r);
  float part[32];
#pragma unroll
  for (int i = 0; i < 32; ++i) part[i] = 0.f;
#pragma unroll
  for (int df = 0; df < 16; ++df) {
    const float4* cwv = (const float4*)(Cw + ((size_t)h * 256 + df * 16 + l15) * 8);
    float4 c0 = cwv[0], c1 = cwv[1];
#pragma unroll
    for (int r = 0; r < 4; ++r) {
      float ov = o_acc[df][r] * rcl[r];
      part[r * 8 + 0] += ov * c0.x;
      part[r * 8 + 1] += ov * c0.y;
      part[r * 8 + 2] += ov * c0.z;
      part[r * 8 + 3] += ov * c0.w;
      part[r * 8 + 4] += ov * c1.x;
      part[r * 8 + 5] += ov * c1.y;
      part[r * 8 + 6] += ov * c1.z;
      part[r * 8 + 7] += ov * c1.w;
    }
  }
#pragma unroll
  for (int i = 0; i < 32; ++i) {
    float v = part[i];
    v += __shfl_xor(v, 1);
    v += __shfl_xor(v, 2);
    v += __shfl_xor(v, 4);
    v += __shfl_xor(v, 8);
    part[i] = v;
  }
  if (l15 == 0) {
#pragma unroll
    for (int r = 0; r < 4; ++r) {
      int s = qbase + w * 16 + quad * 4 + r;
#pragma unroll
      for (int j = 0; j < 8; ++j)
        atomicAdd(&out[((size_t)b * S_ + s) * 8 + j], part[r * 8 + j]);
    }
  }
}

extern "C" void kernel_launch(void* const* d_in, const int* in_sizes, int n_in,
                              void* d_out, int out_size, void* d_ws, size_t ws_size,
                              hipStream_t stream) {
  const float* x  = (const float*)d_in[0];
  const float* bo = (const float*)d_in[1];
  const float* Qw = (const float*)d_in[2];
  const float* Qb = (const float*)d_in[3];
  const float* Kw = (const float*)d_in[4];
  const float* Kb = (const float*)d_in[5];
  const float* Vw = (const float*)d_in[6];
  const float* Vb = (const float*)d_in[7];
  const float* Cw = (const float*)d_in[8];
  const float* Cb = (const float*)d_in[9];
  float* out = (float*)d_out;

  const size_t NW  = (size_t)H_ * 256 * 256;
  const size_t NHB = (size_t)B_ * S_ * 256;
  const size_t ALN = 256;
  auto pad = [](size_t b) { return (b + 255) & ~(size_t)255; };

  // pick largest head-chunk HC in {8,4,2,1} whose scratch fits ws_size
  // (q hi/lo no longer materialized — only k_hi and v_t chunks)
  int HC = 8;
  while (HC > 1) {
    size_t need = 6 * pad(NW * 2) + 2 * pad((size_t)HC * NHB * 2) + ALN;
    if (need <= ws_size) break;
    HC >>= 1;
  }

  char* base = (char*)d_ws;
  size_t off = 0;
  auto carve = [&](size_t nelem) -> _Float16* {
    _Float16* p = (_Float16*)(base + off);
    off += pad(nelem * 2);
    return p;
  };
  _Float16* qwt_hi = carve(NW); _Float16* qwt_lo = carve(NW);
  _Float16* kwt_hi = carve(NW); _Float16* kwt_lo = carve(NW);
  _Float16* vwt_hi = carve(NW); _Float16* vwt_lo = carve(NW);
  const size_t NC = (size_t)HC * NHB;
  _Float16* k_hi = carve(NC);
  _Float16* v_t  = carve(NC);

  dim3 wg(4, 4, 8);
  split_w_kernel<<<wg, 256, 0, stream>>>(Qw, qwt_hi, qwt_lo);
  split_w_kernel<<<wg, 256, 0, stream>>>(Kw, kwt_hi, kwt_lo);
  split_w_kernel<<<wg, 256, 0, stream>>>(Vw, vwt_hi, vwt_lo);
  out_init_kernel<<<(B_ * S_ * 8) / 256, 256, 0, stream>>>(out, Cb);

  for (int h0 = 0; h0 < H_; h0 += HC) {
    dim3 pg(16, 2, HC * 8);
    proj_kernel<2><<<pg, 256, 0, stream>>>(x, kwt_hi, kwt_lo, Kb, 1.0f, h0, k_hi, nullptr);
    proj_kernel<1><<<pg, 256, 0, stream>>>(x, vwt_hi, vwt_lo, Vb, 1.0f, h0, v_t, nullptr);
    dim3 fg(32, HC * 8);
    flash_kernel<<<fg, 256, 0, stream>>>(bo, qwt_hi, qwt_lo, Qb, k_hi, v_t, Cw, out, h0);
  }
}